// Round 11
// baseline (366.614 us; speedup 1.0000x reference)
//
#include <hip/hip_runtime.h>
#include <hip/hip_bf16.h>

typedef __bf16 bf16_t;
typedef __bf16 bf16x4 __attribute__((ext_vector_type(4)));
typedef __bf16 bf16x8 __attribute__((ext_vector_type(8)));
typedef float f32x4 __attribute__((ext_vector_type(4)));

#define MFMA16(a, b, c) __builtin_amdgcn_mfma_f32_16x16x32_bf16((a), (b), (c), 0, 0, 0)

#if defined(__has_builtin) && __has_builtin(__builtin_amdgcn_exp2f)
#define EXP2F(x) __builtin_amdgcn_exp2f(x)
#else
#define EXP2F(x) exp2f(x)
#endif

__device__ __forceinline__ void async_copy16(const void* g, void* l) {
#if defined(__has_builtin) && __has_builtin(__builtin_amdgcn_global_load_lds)
  __builtin_amdgcn_global_load_lds((__attribute__((address_space(1))) void*)g,
                                   (__attribute__((address_space(3))) void*)l, 16, 0, 0);
#else
  *(bf16x8*)l = *(const bf16x8*)g;
#endif
}

// tanh-approx GELU in sigmoid form: x*sigmoid(2c(x+0.044715x^3)); |err|<~3e-3
__device__ __forceinline__ float gelu_f(float x) {
  float u = x * (1.5957691216057308f + 0.07135481283f * x * x);
  return x / (1.0f + __expf(-u));
}

// ---------------- weight fp32 -> bf16 converts (merged dispatches) -----------
__global__ __launch_bounds__(256) void cvt4_k(const float* __restrict__ s0,
                                              const float* __restrict__ s1,
                                              const float* __restrict__ s2,
                                              const float* __restrict__ s3,
                                              bf16_t* __restrict__ d0,
                                              bf16_t* __restrict__ d1,
                                              bf16_t* __restrict__ d2,
                                              bf16_t* __restrict__ d3) {
  const int y = blockIdx.y;
  const float* s = (y == 0) ? s0 : (y == 1) ? s1 : (y == 2) ? s2 : s3;
  bf16_t* d = (y == 0) ? d0 : (y == 1) ? d1 : (y == 2) ? d2 : d3;
  int i = (blockIdx.x * 256 + threadIdx.x) * 4;
  float4 f = *(const float4*)(s + i);
  d[i + 0] = (bf16_t)f.x;
  d[i + 1] = (bf16_t)f.y;
  d[i + 2] = (bf16_t)f.z;
  d[i + 3] = (bf16_t)f.w;
}

__global__ __launch_bounds__(256) void cvt2_k(const float* __restrict__ s0,
                                              const float* __restrict__ s1,
                                              bf16_t* __restrict__ d0,
                                              bf16_t* __restrict__ d1) {
  const int y = blockIdx.y;
  const float* s = (y == 0) ? s0 : s1;
  bf16_t* d = (y == 0) ? d0 : d1;
  int i = (blockIdx.x * 256 + threadIdx.x) * 4;
  float4 f = *(const float4*)(s + i);
  d[i + 0] = (bf16_t)f.x;
  d[i + 1] = (bf16_t)f.y;
  d[i + 2] = (bf16_t)f.z;
  d[i + 3] = (bf16_t)f.w;
}

// ---------------- layernorm over 1024 cols, one block per row ----------------
__global__ __launch_bounds__(256) void ln_k(const float* __restrict__ x,
                                            const float* __restrict__ g,
                                            const float* __restrict__ b,
                                            bf16_t* __restrict__ o) {
  __shared__ float red[8];
  const int t = threadIdx.x;
  const size_t row = blockIdx.x;
  float4 xv = ((const float4*)(x + row * 1024))[t];
  float s = xv.x + xv.y + xv.z + xv.w;
  float s2 = xv.x * xv.x + xv.y * xv.y + xv.z * xv.z + xv.w * xv.w;
#pragma unroll
  for (int off = 1; off < 64; off <<= 1) {
    s += __shfl_xor(s, off);
    s2 += __shfl_xor(s2, off);
  }
  if ((t & 63) == 0) {
    red[t >> 6] = s;
    red[4 + (t >> 6)] = s2;
  }
  __syncthreads();
  s = red[0] + red[1] + red[2] + red[3];
  s2 = red[4] + red[5] + red[6] + red[7];
  const float mu = s * (1.0f / 1024.0f);
  const float rstd = rsqrtf(s2 * (1.0f / 1024.0f) - mu * mu + 1e-5f);
  float4 gv = ((const float4*)g)[t];
  float4 bv = ((const float4*)b)[t];
  bf16_t* op = o + row * 1024 + t * 4;
  op[0] = (bf16_t)((xv.x - mu) * rstd * gv.x + bv.x);
  op[1] = (bf16_t)((xv.y - mu) * rstd * gv.y + bv.y);
  op[2] = (bf16_t)((xv.z - mu) * rstd * gv.z + bv.z);
  op[3] = (bf16_t)((xv.w - mu) * rstd * gv.w + bv.w);
}

// ---------------- 128x128xBK64 GEMM: C = A[M,K] @ W[Nn,K]^T ------------------
template <int EPI>
__global__ __launch_bounds__(256, 4) void gemm_bt(const bf16_t* __restrict__ A,
                                                  const bf16_t* __restrict__ W,
                                                  float* __restrict__ Cf,
                                                  bf16_t* __restrict__ Cb,
                                                  const float* __restrict__ bias,
                                                  const float* __restrict__ resid,
                                                  int M, int Nn, int K) {
  __shared__ alignas(16) bf16_t As[2 * 128 * 32];
  __shared__ alignas(16) bf16_t Bs[2 * 128 * 32];
  const int t = threadIdx.x;
  const int lane = t & 63;
  const int w = t >> 6;
  const int bm = blockIdx.y * 128;
  const int bn = blockIdx.x * 128;
  const int wm = (w >> 1) * 64;
  const int wn = (w & 1) * 64;
  const int lr = lane & 15;
  const int lq = lane >> 4;
  f32x4 acc[4][4] = {};
  const bf16_t* Ap[4];
  const bf16_t* Bp[4];
#pragma unroll
  for (int c = 0; c < 4; ++c) {
    const int flat = c * 256 + t;
    const int p = flat >> 9;
    const int r = (flat >> 2) & 127;
    const int q = flat & 3;
    Ap[c] = A + (size_t)(bm + r) * K + p * 32 + q * 8;
    Bp[c] = W + (size_t)(bn + r) * K + p * 32 + q * 8;
  }
  for (int k0 = 0; k0 < K; k0 += 64) {
#pragma unroll
    for (int c = 0; c < 4; ++c) {
      async_copy16(Ap[c] + k0, &As[(c * 256 + t) * 8]);
      async_copy16(Bp[c] + k0, &Bs[(c * 256 + t) * 8]);
    }
    __syncthreads();
#pragma unroll
    for (int half = 0; half < 2; ++half) {
      const bf16_t* Ash = &As[half * 4096];
      const bf16_t* Bsh = &Bs[half * 4096];
      bf16x8 af[4], bfr[4];
#pragma unroll
      for (int i = 0; i < 4; ++i)
        af[i] = *(const bf16x8*)&Ash[(wm + i * 16 + lr) * 32 + lq * 8];
#pragma unroll
      for (int j = 0; j < 4; ++j)
        bfr[j] = *(const bf16x8*)&Bsh[(wn + j * 16 + lr) * 32 + lq * 8];
#pragma unroll
      for (int i = 0; i < 4; ++i)
#pragma unroll
        for (int j = 0; j < 4; ++j)
          acc[i][j] = MFMA16(af[i], bfr[j], acc[i][j]);
    }
    __syncthreads();
  }
#pragma unroll
  for (int i = 0; i < 4; ++i) {
    const int row = bm + wm + i * 16 + lq * 4;
#pragma unroll
    for (int j = 0; j < 4; ++j) {
      const int col = bn + wn + j * 16 + lr;
      float bcol = (EPI >= 1) ? bias[col] : 0.0f;
#pragma unroll
      for (int r = 0; r < 4; ++r) {
        size_t idx = (size_t)(row + r) * Nn + col;
        float vv = acc[i][j][r];
        if (EPI == 0) {
          Cb[idx] = (bf16_t)vv;
        } else if (EPI == 1) {
          Cf[idx] = vv + bcol + resid[idx];
        } else if (EPI == 2) {
          Cb[idx] = (bf16_t)gelu_f(vv + bcol);
        } else {
          Cf[idx] = gelu_f(vv + bcol) + resid[idx];
        }
      }
    }
  }
}

// ---------------- split-K 128x128 GEMM: fp32 partials, dbuf ------------------
// W2 (M=4096, Nn=1024, Ktot=4096) split into 2 K-halves; 128x128 tile has
// 0.5 ds_read/MFMA (vs 0.75 for 64x128) -> LDS-pipe relief. fp32 partial out.
__global__ __launch_bounds__(256, 2) void gemm_sk(const bf16_t* __restrict__ A,
                                                  const bf16_t* __restrict__ W,
                                                  float* __restrict__ P0,
                                                  float* __restrict__ P1) {
  const int K = 4096, Nn = 1024;
  __shared__ alignas(16) bf16_t As[2][128 * 64];
  __shared__ alignas(16) bf16_t Bs[2][128 * 64];
  const int t = threadIdx.x;
  const int lane = t & 63;
  const int w = t >> 6;
  const int bm = blockIdx.y * 128;
  const int bn = blockIdx.x * 128;
  const int sp = blockIdx.z;
  float* Cf = sp ? P1 : P0;
  const int kbase = sp * 2048;
  const int wm = (w >> 1) * 64;
  const int wn = (w & 1) * 64;
  const int lr = lane & 15;
  const int lq = lane >> 4;
  f32x4 acc[4][4] = {};
  const bf16_t* Ap[4];
  const bf16_t* Bp[4];
#pragma unroll
  for (int c = 0; c < 4; ++c) {
    const int flat = c * 256 + t;
    const int p = flat >> 9;
    const int r = (flat >> 2) & 127;
    const int q = flat & 3;
    Ap[c] = A + (size_t)(bm + r) * K + kbase + p * 32 + q * 8;
    Bp[c] = W + (size_t)(bn + r) * K + kbase + p * 32 + q * 8;
  }
  // prologue: stage first tile into buffer 0
#pragma unroll
  for (int c = 0; c < 4; ++c) {
    async_copy16(Ap[c], &As[0][(c * 256 + t) * 8]);
    async_copy16(Bp[c], &Bs[0][(c * 256 + t) * 8]);
  }
  int buf = 0;
  for (int k0 = 0; k0 < 2048; k0 += 64) {
    __syncthreads();  // drains current buffer's loads (in flight one full iter)
    const int nb = buf ^ 1;
    if (k0 + 64 < 2048) {
#pragma unroll
      for (int c = 0; c < 4; ++c) {
        async_copy16(Ap[c] + k0 + 64, &As[nb][(c * 256 + t) * 8]);
        async_copy16(Bp[c] + k0 + 64, &Bs[nb][(c * 256 + t) * 8]);
      }
    }
#pragma unroll
    for (int half = 0; half < 2; ++half) {
      const bf16_t* Ash = &As[buf][half * 4096];
      const bf16_t* Bsh = &Bs[buf][half * 4096];
      bf16x8 af[4], bfr[4];
#pragma unroll
      for (int i = 0; i < 4; ++i)
        af[i] = *(const bf16x8*)&Ash[(wm + i * 16 + lr) * 32 + lq * 8];
#pragma unroll
      for (int j = 0; j < 4; ++j)
        bfr[j] = *(const bf16x8*)&Bsh[(wn + j * 16 + lr) * 32 + lq * 8];
#pragma unroll
      for (int i = 0; i < 4; ++i)
#pragma unroll
        for (int j = 0; j < 4; ++j)
          acc[i][j] = MFMA16(af[i], bfr[j], acc[i][j]);
    }
    buf = nb;
  }
#pragma unroll
  for (int i = 0; i < 4; ++i) {
    const int row = bm + wm + i * 16 + lq * 4;
#pragma unroll
    for (int j = 0; j < 4; ++j) {
      const int col = bn + wn + j * 16 + lr;
#pragma unroll
      for (int r = 0; r < 4; ++r)
        Cf[(size_t)(row + r) * Nn + col] = acc[i][j][r];
    }
  }
}

// ---------------- W2 epilogue: dout = gelu(p0+p1+bias) + resid ---------------
// 4096 rows x 1024 cols; one block covers 1024 elements -> grid 4096.
__global__ __launch_bounds__(256) void w2_epi(const float* __restrict__ P0,
                                              const float* __restrict__ P1,
                                              const float* __restrict__ bias,
                                              const float* __restrict__ resid,
                                              float* __restrict__ dout) {
  const size_t i = ((size_t)blockIdx.x * 256 + threadIdx.x) * 4;
  const int col = threadIdx.x * 4;  // i % 1024 (1024 elems per block, row-aligned)
  float4 p0 = *(const float4*)(P0 + i);
  float4 p1 = *(const float4*)(P1 + i);
  float4 bv = *(const float4*)(bias + col);
  float4 rv = *(const float4*)(resid + i);
  float4 o;
  o.x = gelu_f(p0.x + p1.x + bv.x) + rv.x;
  o.y = gelu_f(p0.y + p1.y + bv.y) + rv.y;
  o.z = gelu_f(p0.z + p1.z + bv.z) + rv.z;
  o.w = gelu_f(p0.w + p1.w + bv.w) + rv.w;
  *(float4*)(dout + i) = o;
}

// ---------------- 64x128xBK64 GEMM, dbuf + XCD-locality swizzle --------------
// EPI 1: +bias +resid -> fp32 (Wo)
template <int EPI>
__global__ __launch_bounds__(256, 4) void gemm64_bt(const bf16_t* __restrict__ A,
                                                    const bf16_t* __restrict__ W,
                                                    float* __restrict__ Cf,
                                                    const float* __restrict__ bias,
                                                    const float* __restrict__ resid,
                                                    int M, int Nn, int K) {
  __shared__ alignas(16) bf16_t As[2][2 * 64 * 32];
  __shared__ alignas(16) bf16_t Bs[2][2 * 128 * 32];
  const int t = threadIdx.x;
  const int lane = t & 63;
  const int w = t >> 6;
  const int lin = blockIdx.x + 8 * blockIdx.y;
  const int bm = ((lin & 7) * 8 + (lin >> 6)) * 64;
  const int bn = ((lin >> 3) & 7) * 128;
  const int wm = (w >> 1) * 32;
  const int wn = (w & 1) * 64;
  const int lr = lane & 15;
  const int lq = lane >> 4;
  f32x4 acc[2][4] = {};
  const bf16_t* Ap[2];
  const bf16_t* Bp[4];
#pragma unroll
  for (int c = 0; c < 2; ++c) {
    const int flat = c * 256 + t;
    const int p = flat >> 8;
    const int r = (flat >> 2) & 63;
    const int q = flat & 3;
    Ap[c] = A + (size_t)(bm + r) * K + p * 32 + q * 8;
  }
#pragma unroll
  for (int c = 0; c < 4; ++c) {
    const int flat = c * 256 + t;
    const int p = flat >> 9;
    const int r = (flat >> 2) & 127;
    const int q = flat & 3;
    Bp[c] = W + (size_t)(bn + r) * K + p * 32 + q * 8;
  }
#pragma unroll
  for (int c = 0; c < 2; ++c) async_copy16(Ap[c], &As[0][(c * 256 + t) * 8]);
#pragma unroll
  for (int c = 0; c < 4; ++c) async_copy16(Bp[c], &Bs[0][(c * 256 + t) * 8]);
  int buf = 0;
  for (int k0 = 0; k0 < K; k0 += 64) {
    __syncthreads();
    const int nb = buf ^ 1;
    if (k0 + 64 < K) {
#pragma unroll
      for (int c = 0; c < 2; ++c)
        async_copy16(Ap[c] + k0 + 64, &As[nb][(c * 256 + t) * 8]);
#pragma unroll
      for (int c = 0; c < 4; ++c)
        async_copy16(Bp[c] + k0 + 64, &Bs[nb][(c * 256 + t) * 8]);
    }
#pragma unroll
    for (int half = 0; half < 2; ++half) {
      const bf16_t* Ash = &As[buf][half * 2048];
      const bf16_t* Bsh = &Bs[buf][half * 4096];
      bf16x8 af[2], bfr[4];
#pragma unroll
      for (int i = 0; i < 2; ++i)
        af[i] = *(const bf16x8*)&Ash[(wm + i * 16 + lr) * 32 + lq * 8];
#pragma unroll
      for (int j = 0; j < 4; ++j)
        bfr[j] = *(const bf16x8*)&Bsh[(wn + j * 16 + lr) * 32 + lq * 8];
#pragma unroll
      for (int i = 0; i < 2; ++i)
#pragma unroll
        for (int j = 0; j < 4; ++j)
          acc[i][j] = MFMA16(af[i], bfr[j], acc[i][j]);
    }
    buf = nb;
  }
#pragma unroll
  for (int i = 0; i < 2; ++i) {
    const int row = bm + wm + i * 16 + lq * 4;
#pragma unroll
    for (int j = 0; j < 4; ++j) {
      const int col = bn + wn + j * 16 + lr;
      float bcol = bias[col];
#pragma unroll
      for (int r = 0; r < 4; ++r) {
        size_t idx = (size_t)(row + r) * Nn + col;
        float vv = acc[i][j][r];
        if (EPI == 1)
          Cf[idx] = vv + bcol + resid[idx];
        else
          Cf[idx] = gelu_f(vv + bcol) + resid[idx];
      }
    }
  }
}

// ---------------- V transpose v2: LDS-tiled, coalesced both sides ------------
__global__ __launch_bounds__(256) void vtrans_k(const bf16_t* __restrict__ vsrc,
                                                bf16_t* __restrict__ vt) {
  __shared__ alignas(16) bf16_t Ls[64 * 64];
  const int t = threadIdx.x;
  const int nt = blockIdx.x;  // n tile (64 wide)
  const int bh = blockIdx.y;  // b*16+h
  const int b = bh >> 4;
  const int h = bh & 15;
#pragma unroll
  for (int rep = 0; rep < 2; ++rep) {
    const int cl = rep * 256 + t;
    const int r = cl >> 3;             // n row 0..63
    const int c = (cl & 7) ^ (r & 7);  // logical d-chunk to fetch
    async_copy16(vsrc + (size_t)(b * 2048 + nt * 64 + r) * 1024 + h * 64 + c * 8,
                 &Ls[cl * 8]);
  }
  __syncthreads();
  const int nc = (t & 7) * 8;
#pragma unroll
  for (int rep = 0; rep < 2; ++rep) {
    const int dr = (t >> 3) + rep * 32;  // d row 0..63
    bf16x8 vv;
#pragma unroll
    for (int j = 0; j < 8; ++j)
      vv[j] = Ls[(nc + j) * 64 + ((dr >> 3) ^ j) * 8 + (dr & 7)];
    *(bf16x8*)&vt[(size_t)(bh * 64 + dr) * 2048 + nt * 64 + nc] = vv;
  }
}

// ---------------- fused QKV GEMM (BK=64); Q output pre-scaled ----------------
__global__ __launch_bounds__(256) void gemm_qkv(const bf16_t* __restrict__ A,
                                                const bf16_t* __restrict__ W0,
                                                const bf16_t* __restrict__ W1,
                                                const bf16_t* __restrict__ W2,
                                                bf16_t* __restrict__ C0,
                                                bf16_t* __restrict__ C1,
                                                bf16_t* __restrict__ C2) {
  const int z = blockIdx.z;
  const bf16_t* W = (z == 0) ? W0 : ((z == 1) ? W1 : W2);
  bf16_t* Cb = (z == 0) ? C0 : ((z == 1) ? C1 : C2);
  const float osc = (z == 0) ? 0.045084220027780106f : 1.0f;
  const int K = 1024, Nn = 1024;
  __shared__ alignas(16) bf16_t As[2 * 128 * 32];
  __shared__ alignas(16) bf16_t Bs[2 * 128 * 32];
  const int t = threadIdx.x;
  const int lane = t & 63;
  const int w = t >> 6;
  const int bm = blockIdx.y * 128;
  const int bn = blockIdx.x * 128;
  const int wm = (w >> 1) * 64;
  const int wn = (w & 1) * 64;
  const int lr = lane & 15;
  const int lq = lane >> 4;
  f32x4 acc[4][4] = {};
  const bf16_t* Ap[4];
  const bf16_t* Bp[4];
#pragma unroll
  for (int c = 0; c < 4; ++c) {
    const int flat = c * 256 + t;
    const int p = flat >> 9;
    const int r = (flat >> 2) & 127;
    const int q = flat & 3;
    Ap[c] = A + (size_t)(bm + r) * K + p * 32 + q * 8;
    Bp[c] = W + (size_t)(bn + r) * K + p * 32 + q * 8;
  }
  for (int k0 = 0; k0 < K; k0 += 64) {
#pragma unroll
    for (int c = 0; c < 4; ++c) {
      async_copy16(Ap[c] + k0, &As[(c * 256 + t) * 8]);
      async_copy16(Bp[c] + k0, &Bs[(c * 256 + t) * 8]);
    }
    __syncthreads();
#pragma unroll
    for (int half = 0; half < 2; ++half) {
      const bf16_t* Ash = &As[half * 4096];
      const bf16_t* Bsh = &Bs[half * 4096];
      bf16x8 af[4], bfr[4];
#pragma unroll
      for (int i = 0; i < 4; ++i)
        af[i] = *(const bf16x8*)&Ash[(wm + i * 16 + lr) * 32 + lq * 8];
#pragma unroll
      for (int j = 0; j < 4; ++j)
        bfr[j] = *(const bf16x8*)&Bsh[(wn + j * 16 + lr) * 32 + lq * 8];
#pragma unroll
      for (int i = 0; i < 4; ++i)
#pragma unroll
        for (int j = 0; j < 4; ++j)
          acc[i][j] = MFMA16(af[i], bfr[j], acc[i][j]);
    }
    __syncthreads();
  }
#pragma unroll
  for (int i = 0; i < 4; ++i) {
    const int row = bm + wm + i * 16 + lq * 4;
#pragma unroll
    for (int j = 0; j < 4; ++j) {
      const int col = bn + wn + j * 16 + lr;
#pragma unroll
      for (int r = 0; r < 4; ++r)
        Cb[(size_t)(row + r) * Nn + col] = (bf16_t)(acc[i][j][r] * osc);
    }
  }
}

// ---------------- flash attention v8: 128q tiles + split-K over keys ---------
__global__ __launch_bounds__(256) void flash_attn(const bf16_t* __restrict__ q,
                                                  const bf16_t* __restrict__ k,
                                                  const bf16_t* __restrict__ vt,
                                                  bf16_t* __restrict__ Opart,
                                                  float* __restrict__ lpart) {
  constexpr int PSP = 72;
  __shared__ alignas(16) bf16_t Ks[64 * 64];
  __shared__ alignas(16) bf16_t Vs[64 * 64];
  __shared__ alignas(16) bf16_t Ps[4][32 * PSP];
  const int t = threadIdx.x;
  const int lane = t & 63;
  const int w = t >> 6;
  const int lr = lane & 15;
  const int lq = lane >> 4;
  const int qt = blockIdx.x;   // query tile 0..15 (128 wide)
  const int bh = blockIdx.y;   // b*16+h
  const int sp = blockIdx.z;   // key split 0..1
  const int b = bh >> 4;
  const int h = bh & 15;
  const size_t rowbase = (size_t)b * 2048;
  const int hcol = h * 64;
  const bf16_t* vtp = vt + (size_t)bh * 64 * 2048;

  bf16x8 qf[2][2];
#pragma unroll
  for (int u = 0; u < 2; ++u) {
    size_t qrow = rowbase + qt * 128 + w * 32 + u * 16 + lr;
    const bf16_t* qp = q + qrow * 1024 + hcol + lq * 8;
    qf[u][0] = *(const bf16x8*)qp;
    qf[u][1] = *(const bf16x8*)(qp + 32);
  }
  bf16x8 ones;
#pragma unroll
  for (int j = 0; j < 8; ++j) ones[j] = (bf16_t)1.0f;
  f32x4 of[2][4] = {};
  f32x4 ofl[2] = {};

  for (int kt = sp * 16; kt < sp * 16 + 16; ++kt) {
    const size_t krow0 = rowbase + kt * 64;
#pragma unroll
    for (int rep = 0; rep < 2; ++rep) {
      const int cl = rep * 256 + t;
      const int r = cl >> 3;
      const int c = (cl & 7) ^ (r & 7);
      async_copy16(k + (krow0 + r) * 1024 + hcol + c * 8, &Ks[cl * 8]);
      async_copy16(vtp + (size_t)r * 2048 + kt * 64 + c * 8, &Vs[cl * 8]);
    }
    __syncthreads();
    f32x4 sc[2][4];
#pragma unroll
    for (int s = 0; s < 4; ++s) {
      const int r2 = s * 16 + lr;
      bf16x8 kf0 = *(const bf16x8*)&Ks[r2 * 64 + ((lq) ^ (r2 & 7)) * 8];
      bf16x8 kf1 = *(const bf16x8*)&Ks[r2 * 64 + ((4 + lq) ^ (r2 & 7)) * 8];
#pragma unroll
      for (int u = 0; u < 2; ++u) {
        f32x4 c = {};
        c = MFMA16(kf0, qf[u][0], c);
        c = MFMA16(kf1, qf[u][1], c);
        sc[u][s] = c;
      }
    }
#pragma unroll
    for (int u = 0; u < 2; ++u)
#pragma unroll
      for (int s = 0; s < 4; ++s) {
        bf16x4 pv;
#pragma unroll
        for (int r = 0; r < 4; ++r) pv[r] = (bf16_t)EXP2F(sc[u][s][r]);
        *(bf16x4*)&Ps[w][(u * 16 + lr) * PSP + s * 16 + lq * 4] = pv;
      }
    bf16x8 pf[2][2];
#pragma unroll
    for (int u = 0; u < 2; ++u) {
      pf[u][0] = *(const bf16x8*)&Ps[w][(u * 16 + lr) * PSP + lq * 8];
      pf[u][1] = *(const bf16x8*)&Ps[w][(u * 16 + lr) * PSP + 32 + lq * 8];
      ofl[u] = MFMA16(pf[u][0], ones, ofl[u]);
      ofl[u] = MFMA16(pf[u][1], ones, ofl[u]);
    }
#pragma unroll
    for (int d = 0; d < 4; ++d) {
      const int rv = d * 16 + lr;
      bf16x8 vf0 = *(const bf16x8*)&Vs[rv * 64 + ((lq) ^ (rv & 7)) * 8];
      bf16x8 vf1 = *(const bf16x8*)&Vs[rv * 64 + ((4 + lq) ^ (rv & 7)) * 8];
#pragma unroll
      for (int u = 0; u < 2; ++u) {
        of[u][d] = MFMA16(pf[u][0], vf0, of[u][d]);
        of[u][d] = MFMA16(pf[u][1], vf1, of[u][d]);
      }
    }
    __syncthreads();
  }
  bf16_t* Op = Opart + (size_t)sp * 4096 * 1024;
  float* lp = lpart + (size_t)sp * 4096 * 16;
#pragma unroll
  for (int u = 0; u < 2; ++u) {
    const size_t grow0 = rowbase + qt * 128 + w * 32 + u * 16 + lq * 4;
#pragma unroll
    for (int r = 0; r < 4; ++r) {
#pragma unroll
      for (int d = 0; d < 4; ++d)
        Op[(grow0 + r) * 1024 + hcol + d * 16 + lr] = (bf16_t)of[u][d][r];
      if (lr == 0) lp[(grow0 + r) * 16 + h] = ofl[u][r];
    }
  }
}

// ---------------- split-K combine: attn = (O0+O1)/(l0+l1) --------------------
__global__ __launch_bounds__(256) void combine_k(const bf16_t* __restrict__ Opart,
                                                 const float* __restrict__ lpart,
                                                 bf16_t* __restrict__ attn) {
  const size_t row = blockIdx.x;
  const int t = threadIdx.x;
  const int h = t >> 4;
  const float inv =
      1.0f / (lpart[row * 16 + h] + lpart[4096 * 16 + row * 16 + h]);
  const size_t i = row * 1024 + t * 4;
  bf16x4 a = *(const bf16x4*)&Opart[i];
  bf16x4 bvv = *(const bf16x4*)&Opart[(size_t)4096 * 1024 + i];
  bf16x4 o;
#pragma unroll
  for (int j = 0; j < 4; ++j) o[j] = (bf16_t)(((float)a[j] + (float)bvv[j]) * inv);
  *(bf16x4*)&attn[i] = o;
}

extern "C" void kernel_launch(void* const* d_in, const int* in_sizes, int n_in,
                              void* d_out, int out_size, void* d_ws, size_t ws_size,
                              hipStream_t stream) {
  (void)in_sizes;
  (void)n_in;
  (void)out_size;
  (void)ws_size;
  const float* x = (const float*)d_in[0];
  const float* la1g = (const float*)d_in[1];
  const float* la1b = (const float*)d_in[2];
  const float* Wq = (const float*)d_in[3];
  const float* Wk = (const float*)d_in[4];
  const float* Wv = (const float*)d_in[5];
  const float* Wo = (const float*)d_in[6];
  const float* bo = (const float*)d_in[7];
  const float* la2g = (const float*)d_in[8];
  const float* la2b = (const float*)d_in[9];
  const float* W1 = (const float*)d_in[10];
  const float* b1 = (const float*)d_in[11];
  const float* W2 = (const float*)d_in[12];
  const float* b2 = (const float*)d_in[13];
  char* ws = (char*)d_ws;
  const size_t MB = (size_t)1 << 20;
  bf16_t* wq_b = (bf16_t*)(ws + 0 * MB);
  bf16_t* wk_b = (bf16_t*)(ws + 2 * MB);
  bf16_t* wv_b = (bf16_t*)(ws + 4 * MB);
  bf16_t* wo_b = (bf16_t*)(ws + 6 * MB);
  bf16_t* w1_b = (bf16_t*)(ws + 8 * MB);
  bf16_t* w2_b = (bf16_t*)(ws + 16 * MB);
  bf16_t* hbuf = (bf16_t*)(ws + 24 * MB);  // reused as vt after QKV
  bf16_t* qb = (bf16_t*)(ws + 32 * MB);
  bf16_t* kb = (bf16_t*)(ws + 40 * MB);
  bf16_t* vb = (bf16_t*)(ws + 48 * MB);
  bf16_t* attn = (bf16_t*)(ws + 56 * MB);
  float* outb = (float*)(ws + 64 * MB);      // 16 MB fp32
  bf16_t* h2 = (bf16_t*)(ws + 80 * MB);      // 8 MB
  bf16_t* m1 = (bf16_t*)(ws + 88 * MB);      // 32 MB (88-120)
  bf16_t* vt = hbuf;
  // flash split-K scratch (dead after combine): overlays outb/h2 slots
  bf16_t* Opart = (bf16_t*)(ws + 64 * MB);   // 2 x 8 MB bf16
  float* lpart = (float*)(ws + 80 * MB);     // 512 KB fp32
  // W2 split-K partials: overlay slots dead after flash (vt 24-32, qb 32-48)
  float* p0 = (float*)(ws + 24 * MB);        // 16 MB fp32 (24-40)
  float* p1 = (float*)(ws + 40 * MB);        // 16 MB fp32 (40-56)
  float* dout = (float*)d_out;

  cvt4_k<<<dim3(1024, 4), 256, 0, stream>>>(Wq, Wk, Wv, Wo, wq_b, wk_b, wv_b, wo_b);
  cvt2_k<<<dim3(4096, 2), 256, 0, stream>>>(W1, W2, w1_b, w2_b);
  ln_k<<<4096, 256, 0, stream>>>(x, la1g, la1b, hbuf);
  gemm_qkv<<<dim3(8, 32, 3), 256, 0, stream>>>(hbuf, wq_b, wk_b, wv_b, qb, kb, vb);
  vtrans_k<<<dim3(32, 32), 256, 0, stream>>>(vb, vt);
  flash_attn<<<dim3(16, 32, 2), 256, 0, stream>>>(qb, kb, vt, Opart, lpart);
  combine_k<<<4096, 256, 0, stream>>>(Opart, lpart, attn);
  gemm64_bt<1><<<dim3(8, 64), 256, 0, stream>>>(attn, wo_b, outb, bo, x, 4096, 1024, 1024);
  ln_k<<<4096, 256, 0, stream>>>(outb, la2g, la2b, h2);
  gemm_bt<2><<<dim3(32, 32), 256, 0, stream>>>(h2, w1_b, nullptr, m1, b1, nullptr, 4096, 4096, 1024);
  // W2: split-K 128x128 partials + fused epilogue (4096x1024 elems -> 4096 blocks)
  gemm_sk<<<dim3(8, 32, 2), 256, 0, stream>>>(m1, w2_b, p0, p1);
  w2_epi<<<4096, 256, 0, stream>>>(p0, p1, b2, outb, dout);
}

// Round 12
// 366.210 us; speedup vs baseline: 1.0011x; 1.0011x over previous
//
#include <hip/hip_runtime.h>
#include <hip/hip_bf16.h>

typedef __bf16 bf16_t;
typedef __bf16 bf16x4 __attribute__((ext_vector_type(4)));
typedef __bf16 bf16x8 __attribute__((ext_vector_type(8)));
typedef float f32x4 __attribute__((ext_vector_type(4)));

#define MFMA16(a, b, c) __builtin_amdgcn_mfma_f32_16x16x32_bf16((a), (b), (c), 0, 0, 0)

#if defined(__has_builtin) && __has_builtin(__builtin_amdgcn_exp2f)
#define EXP2F(x) __builtin_amdgcn_exp2f(x)
#else
#define EXP2F(x) exp2f(x)
#endif

__device__ __forceinline__ void async_copy16(const void* g, void* l) {
#if defined(__has_builtin) && __has_builtin(__builtin_amdgcn_global_load_lds)
  __builtin_amdgcn_global_load_lds((__attribute__((address_space(1))) void*)g,
                                   (__attribute__((address_space(3))) void*)l, 16, 0, 0);
#else
  *(bf16x8*)l = *(const bf16x8*)g;
#endif
}

// tanh-approx GELU in sigmoid form: x*sigmoid(2c(x+0.044715x^3)); |err|<~3e-3
__device__ __forceinline__ float gelu_f(float x) {
  float u = x * (1.5957691216057308f + 0.07135481283f * x * x);
  return x / (1.0f + __expf(-u));
}

// ---------------- weight fp32 -> bf16 converts (merged dispatches) -----------
__global__ __launch_bounds__(256) void cvt4_k(const float* __restrict__ s0,
                                              const float* __restrict__ s1,
                                              const float* __restrict__ s2,
                                              const float* __restrict__ s3,
                                              bf16_t* __restrict__ d0,
                                              bf16_t* __restrict__ d1,
                                              bf16_t* __restrict__ d2,
                                              bf16_t* __restrict__ d3) {
  const int y = blockIdx.y;
  const float* s = (y == 0) ? s0 : (y == 1) ? s1 : (y == 2) ? s2 : s3;
  bf16_t* d = (y == 0) ? d0 : (y == 1) ? d1 : (y == 2) ? d2 : d3;
  int i = (blockIdx.x * 256 + threadIdx.x) * 4;
  float4 f = *(const float4*)(s + i);
  d[i + 0] = (bf16_t)f.x;
  d[i + 1] = (bf16_t)f.y;
  d[i + 2] = (bf16_t)f.z;
  d[i + 3] = (bf16_t)f.w;
}

__global__ __launch_bounds__(256) void cvt2_k(const float* __restrict__ s0,
                                              const float* __restrict__ s1,
                                              bf16_t* __restrict__ d0,
                                              bf16_t* __restrict__ d1) {
  const int y = blockIdx.y;
  const float* s = (y == 0) ? s0 : s1;
  bf16_t* d = (y == 0) ? d0 : d1;
  int i = (blockIdx.x * 256 + threadIdx.x) * 4;
  float4 f = *(const float4*)(s + i);
  d[i + 0] = (bf16_t)f.x;
  d[i + 1] = (bf16_t)f.y;
  d[i + 2] = (bf16_t)f.z;
  d[i + 3] = (bf16_t)f.w;
}

// ---------------- layernorm over 1024 cols, one block per row ----------------
__global__ __launch_bounds__(256) void ln_k(const float* __restrict__ x,
                                            const float* __restrict__ g,
                                            const float* __restrict__ b,
                                            bf16_t* __restrict__ o) {
  __shared__ float red[8];
  const int t = threadIdx.x;
  const size_t row = blockIdx.x;
  float4 xv = ((const float4*)(x + row * 1024))[t];
  float s = xv.x + xv.y + xv.z + xv.w;
  float s2 = xv.x * xv.x + xv.y * xv.y + xv.z * xv.z + xv.w * xv.w;
#pragma unroll
  for (int off = 1; off < 64; off <<= 1) {
    s += __shfl_xor(s, off);
    s2 += __shfl_xor(s2, off);
  }
  if ((t & 63) == 0) {
    red[t >> 6] = s;
    red[4 + (t >> 6)] = s2;
  }
  __syncthreads();
  s = red[0] + red[1] + red[2] + red[3];
  s2 = red[4] + red[5] + red[6] + red[7];
  const float mu = s * (1.0f / 1024.0f);
  const float rstd = rsqrtf(s2 * (1.0f / 1024.0f) - mu * mu + 1e-5f);
  float4 gv = ((const float4*)g)[t];
  float4 bv = ((const float4*)b)[t];
  bf16_t* op = o + row * 1024 + t * 4;
  op[0] = (bf16_t)((xv.x - mu) * rstd * gv.x + bv.x);
  op[1] = (bf16_t)((xv.y - mu) * rstd * gv.y + bv.y);
  op[2] = (bf16_t)((xv.z - mu) * rstd * gv.z + bv.z);
  op[3] = (bf16_t)((xv.w - mu) * rstd * gv.w + bv.w);
}

// ---------------- 128x128xBK64 GEMM: C = A[M,K] @ W[Nn,K]^T ------------------
template <int EPI>
__global__ __launch_bounds__(256, 4) void gemm_bt(const bf16_t* __restrict__ A,
                                                  const bf16_t* __restrict__ W,
                                                  float* __restrict__ Cf,
                                                  bf16_t* __restrict__ Cb,
                                                  const float* __restrict__ bias,
                                                  const float* __restrict__ resid,
                                                  int M, int Nn, int K) {
  __shared__ alignas(16) bf16_t As[2 * 128 * 32];
  __shared__ alignas(16) bf16_t Bs[2 * 128 * 32];
  const int t = threadIdx.x;
  const int lane = t & 63;
  const int w = t >> 6;
  const int bm = blockIdx.y * 128;
  const int bn = blockIdx.x * 128;
  const int wm = (w >> 1) * 64;
  const int wn = (w & 1) * 64;
  const int lr = lane & 15;
  const int lq = lane >> 4;
  f32x4 acc[4][4] = {};
  const bf16_t* Ap[4];
  const bf16_t* Bp[4];
#pragma unroll
  for (int c = 0; c < 4; ++c) {
    const int flat = c * 256 + t;
    const int p = flat >> 9;
    const int r = (flat >> 2) & 127;
    const int q = flat & 3;
    Ap[c] = A + (size_t)(bm + r) * K + p * 32 + q * 8;
    Bp[c] = W + (size_t)(bn + r) * K + p * 32 + q * 8;
  }
  for (int k0 = 0; k0 < K; k0 += 64) {
#pragma unroll
    for (int c = 0; c < 4; ++c) {
      async_copy16(Ap[c] + k0, &As[(c * 256 + t) * 8]);
      async_copy16(Bp[c] + k0, &Bs[(c * 256 + t) * 8]);
    }
    __syncthreads();
#pragma unroll
    for (int half = 0; half < 2; ++half) {
      const bf16_t* Ash = &As[half * 4096];
      const bf16_t* Bsh = &Bs[half * 4096];
      bf16x8 af[4], bfr[4];
#pragma unroll
      for (int i = 0; i < 4; ++i)
        af[i] = *(const bf16x8*)&Ash[(wm + i * 16 + lr) * 32 + lq * 8];
#pragma unroll
      for (int j = 0; j < 4; ++j)
        bfr[j] = *(const bf16x8*)&Bsh[(wn + j * 16 + lr) * 32 + lq * 8];
#pragma unroll
      for (int i = 0; i < 4; ++i)
#pragma unroll
        for (int j = 0; j < 4; ++j)
          acc[i][j] = MFMA16(af[i], bfr[j], acc[i][j]);
    }
    __syncthreads();
  }
#pragma unroll
  for (int i = 0; i < 4; ++i) {
    const int row = bm + wm + i * 16 + lq * 4;
#pragma unroll
    for (int j = 0; j < 4; ++j) {
      const int col = bn + wn + j * 16 + lr;
      float bcol = (EPI >= 1) ? bias[col] : 0.0f;
#pragma unroll
      for (int r = 0; r < 4; ++r) {
        size_t idx = (size_t)(row + r) * Nn + col;
        float vv = acc[i][j][r];
        if (EPI == 0) {
          Cb[idx] = (bf16_t)vv;
        } else if (EPI == 1) {
          Cf[idx] = vv + bcol + resid[idx];
        } else if (EPI == 2) {
          Cb[idx] = (bf16_t)gelu_f(vv + bcol);
        } else {
          Cf[idx] = gelu_f(vv + bcol) + resid[idx];
        }
      }
    }
  }
}

// ---------------- split-K 128x128 GEMM: fp32 partials, dbuf ------------------
__global__ __launch_bounds__(256, 2) void gemm_sk(const bf16_t* __restrict__ A,
                                                  const bf16_t* __restrict__ W,
                                                  float* __restrict__ P0,
                                                  float* __restrict__ P1) {
  const int K = 4096, Nn = 1024;
  __shared__ alignas(16) bf16_t As[2][128 * 64];
  __shared__ alignas(16) bf16_t Bs[2][128 * 64];
  const int t = threadIdx.x;
  const int lane = t & 63;
  const int w = t >> 6;
  const int bm = blockIdx.y * 128;
  const int bn = blockIdx.x * 128;
  const int sp = blockIdx.z;
  float* Cf = sp ? P1 : P0;
  const int kbase = sp * 2048;
  const int wm = (w >> 1) * 64;
  const int wn = (w & 1) * 64;
  const int lr = lane & 15;
  const int lq = lane >> 4;
  f32x4 acc[4][4] = {};
  const bf16_t* Ap[4];
  const bf16_t* Bp[4];
#pragma unroll
  for (int c = 0; c < 4; ++c) {
    const int flat = c * 256 + t;
    const int p = flat >> 9;
    const int r = (flat >> 2) & 127;
    const int q = flat & 3;
    Ap[c] = A + (size_t)(bm + r) * K + kbase + p * 32 + q * 8;
    Bp[c] = W + (size_t)(bn + r) * K + kbase + p * 32 + q * 8;
  }
#pragma unroll
  for (int c = 0; c < 4; ++c) {
    async_copy16(Ap[c], &As[0][(c * 256 + t) * 8]);
    async_copy16(Bp[c], &Bs[0][(c * 256 + t) * 8]);
  }
  int buf = 0;
  for (int k0 = 0; k0 < 2048; k0 += 64) {
    __syncthreads();
    const int nb = buf ^ 1;
    if (k0 + 64 < 2048) {
#pragma unroll
      for (int c = 0; c < 4; ++c) {
        async_copy16(Ap[c] + k0 + 64, &As[nb][(c * 256 + t) * 8]);
        async_copy16(Bp[c] + k0 + 64, &Bs[nb][(c * 256 + t) * 8]);
      }
    }
#pragma unroll
    for (int half = 0; half < 2; ++half) {
      const bf16_t* Ash = &As[buf][half * 4096];
      const bf16_t* Bsh = &Bs[buf][half * 4096];
      bf16x8 af[4], bfr[4];
#pragma unroll
      for (int i = 0; i < 4; ++i)
        af[i] = *(const bf16x8*)&Ash[(wm + i * 16 + lr) * 32 + lq * 8];
#pragma unroll
      for (int j = 0; j < 4; ++j)
        bfr[j] = *(const bf16x8*)&Bsh[(wn + j * 16 + lr) * 32 + lq * 8];
#pragma unroll
      for (int i = 0; i < 4; ++i)
#pragma unroll
        for (int j = 0; j < 4; ++j)
          acc[i][j] = MFMA16(af[i], bfr[j], acc[i][j]);
    }
    buf = nb;
  }
#pragma unroll
  for (int i = 0; i < 4; ++i) {
    const int row = bm + wm + i * 16 + lq * 4;
#pragma unroll
    for (int j = 0; j < 4; ++j) {
      const int col = bn + wn + j * 16 + lr;
#pragma unroll
      for (int r = 0; r < 4; ++r)
        Cf[(size_t)(row + r) * Nn + col] = acc[i][j][r];
    }
  }
}

// ---------------- W2 epilogue: dout = gelu(p0+p1+bias) + resid ---------------
__global__ __launch_bounds__(256) void w2_epi(const float* __restrict__ P0,
                                              const float* __restrict__ P1,
                                              const float* __restrict__ bias,
                                              const float* __restrict__ resid,
                                              float* __restrict__ dout) {
  const size_t i = ((size_t)blockIdx.x * 256 + threadIdx.x) * 4;
  const int col = threadIdx.x * 4;
  float4 p0 = *(const float4*)(P0 + i);
  float4 p1 = *(const float4*)(P1 + i);
  float4 bv = *(const float4*)(bias + col);
  float4 rv = *(const float4*)(resid + i);
  float4 o;
  o.x = gelu_f(p0.x + p1.x + bv.x) + rv.x;
  o.y = gelu_f(p0.y + p1.y + bv.y) + rv.y;
  o.z = gelu_f(p0.z + p1.z + bv.z) + rv.z;
  o.w = gelu_f(p0.w + p1.w + bv.w) + rv.w;
  *(float4*)(dout + i) = o;
}

// ---------------- 64x128xBK64 GEMM, dbuf + XCD-locality swizzle --------------
template <int EPI>
__global__ __launch_bounds__(256, 4) void gemm64_bt(const bf16_t* __restrict__ A,
                                                    const bf16_t* __restrict__ W,
                                                    float* __restrict__ Cf,
                                                    const float* __restrict__ bias,
                                                    const float* __restrict__ resid,
                                                    int M, int Nn, int K) {
  __shared__ alignas(16) bf16_t As[2][2 * 64 * 32];
  __shared__ alignas(16) bf16_t Bs[2][2 * 128 * 32];
  const int t = threadIdx.x;
  const int lane = t & 63;
  const int w = t >> 6;
  const int lin = blockIdx.x + 8 * blockIdx.y;
  const int bm = ((lin & 7) * 8 + (lin >> 6)) * 64;
  const int bn = ((lin >> 3) & 7) * 128;
  const int wm = (w >> 1) * 32;
  const int wn = (w & 1) * 64;
  const int lr = lane & 15;
  const int lq = lane >> 4;
  f32x4 acc[2][4] = {};
  const bf16_t* Ap[2];
  const bf16_t* Bp[4];
#pragma unroll
  for (int c = 0; c < 2; ++c) {
    const int flat = c * 256 + t;
    const int p = flat >> 8;
    const int r = (flat >> 2) & 63;
    const int q = flat & 3;
    Ap[c] = A + (size_t)(bm + r) * K + p * 32 + q * 8;
  }
#pragma unroll
  for (int c = 0; c < 4; ++c) {
    const int flat = c * 256 + t;
    const int p = flat >> 9;
    const int r = (flat >> 2) & 127;
    const int q = flat & 3;
    Bp[c] = W + (size_t)(bn + r) * K + p * 32 + q * 8;
  }
#pragma unroll
  for (int c = 0; c < 2; ++c) async_copy16(Ap[c], &As[0][(c * 256 + t) * 8]);
#pragma unroll
  for (int c = 0; c < 4; ++c) async_copy16(Bp[c], &Bs[0][(c * 256 + t) * 8]);
  int buf = 0;
  for (int k0 = 0; k0 < K; k0 += 64) {
    __syncthreads();
    const int nb = buf ^ 1;
    if (k0 + 64 < K) {
#pragma unroll
      for (int c = 0; c < 2; ++c)
        async_copy16(Ap[c] + k0 + 64, &As[nb][(c * 256 + t) * 8]);
#pragma unroll
      for (int c = 0; c < 4; ++c)
        async_copy16(Bp[c] + k0 + 64, &Bs[nb][(c * 256 + t) * 8]);
    }
#pragma unroll
    for (int half = 0; half < 2; ++half) {
      const bf16_t* Ash = &As[buf][half * 2048];
      const bf16_t* Bsh = &Bs[buf][half * 4096];
      bf16x8 af[2], bfr[4];
#pragma unroll
      for (int i = 0; i < 2; ++i)
        af[i] = *(const bf16x8*)&Ash[(wm + i * 16 + lr) * 32 + lq * 8];
#pragma unroll
      for (int j = 0; j < 4; ++j)
        bfr[j] = *(const bf16x8*)&Bsh[(wn + j * 16 + lr) * 32 + lq * 8];
#pragma unroll
      for (int i = 0; i < 2; ++i)
#pragma unroll
        for (int j = 0; j < 4; ++j)
          acc[i][j] = MFMA16(af[i], bfr[j], acc[i][j]);
    }
    buf = nb;
  }
#pragma unroll
  for (int i = 0; i < 2; ++i) {
    const int row = bm + wm + i * 16 + lq * 4;
#pragma unroll
    for (int j = 0; j < 4; ++j) {
      const int col = bn + wn + j * 16 + lr;
      float bcol = bias[col];
#pragma unroll
      for (int r = 0; r < 4; ++r) {
        size_t idx = (size_t)(row + r) * Nn + col;
        float vv = acc[i][j][r];
        if (EPI == 1)
          Cf[idx] = vv + bcol + resid[idx];
        else
          Cf[idx] = gelu_f(vv + bcol) + resid[idx];
      }
    }
  }
}

// ---------------- V transpose v2: LDS-tiled, coalesced both sides ------------
__global__ __launch_bounds__(256) void vtrans_k(const bf16_t* __restrict__ vsrc,
                                                bf16_t* __restrict__ vt) {
  __shared__ alignas(16) bf16_t Ls[64 * 64];
  const int t = threadIdx.x;
  const int nt = blockIdx.x;  // n tile (64 wide)
  const int bh = blockIdx.y;  // b*16+h
  const int b = bh >> 4;
  const int h = bh & 15;
#pragma unroll
  for (int rep = 0; rep < 2; ++rep) {
    const int cl = rep * 256 + t;
    const int r = cl >> 3;
    const int c = (cl & 7) ^ (r & 7);
    async_copy16(vsrc + (size_t)(b * 2048 + nt * 64 + r) * 1024 + h * 64 + c * 8,
                 &Ls[cl * 8]);
  }
  __syncthreads();
  const int nc = (t & 7) * 8;
#pragma unroll
  for (int rep = 0; rep < 2; ++rep) {
    const int dr = (t >> 3) + rep * 32;
    bf16x8 vv;
#pragma unroll
    for (int j = 0; j < 8; ++j)
      vv[j] = Ls[(nc + j) * 64 + ((dr >> 3) ^ j) * 8 + (dr & 7)];
    *(bf16x8*)&vt[(size_t)(bh * 64 + dr) * 2048 + nt * 64 + nc] = vv;
  }
}

// ---------------- fused QKV GEMM (BK=64); Q output pre-scaled ----------------
__global__ __launch_bounds__(256) void gemm_qkv(const bf16_t* __restrict__ A,
                                                const bf16_t* __restrict__ W0,
                                                const bf16_t* __restrict__ W1,
                                                const bf16_t* __restrict__ W2,
                                                bf16_t* __restrict__ C0,
                                                bf16_t* __restrict__ C1,
                                                bf16_t* __restrict__ C2) {
  const int z = blockIdx.z;
  const bf16_t* W = (z == 0) ? W0 : ((z == 1) ? W1 : W2);
  bf16_t* Cb = (z == 0) ? C0 : ((z == 1) ? C1 : C2);
  const float osc = (z == 0) ? 0.045084220027780106f : 1.0f;
  const int K = 1024, Nn = 1024;
  __shared__ alignas(16) bf16_t As[2 * 128 * 32];
  __shared__ alignas(16) bf16_t Bs[2 * 128 * 32];
  const int t = threadIdx.x;
  const int lane = t & 63;
  const int w = t >> 6;
  const int bm = blockIdx.y * 128;
  const int bn = blockIdx.x * 128;
  const int wm = (w >> 1) * 64;
  const int wn = (w & 1) * 64;
  const int lr = lane & 15;
  const int lq = lane >> 4;
  f32x4 acc[4][4] = {};
  const bf16_t* Ap[4];
  const bf16_t* Bp[4];
#pragma unroll
  for (int c = 0; c < 4; ++c) {
    const int flat = c * 256 + t;
    const int p = flat >> 9;
    const int r = (flat >> 2) & 127;
    const int q = flat & 3;
    Ap[c] = A + (size_t)(bm + r) * K + p * 32 + q * 8;
    Bp[c] = W + (size_t)(bn + r) * K + p * 32 + q * 8;
  }
  for (int k0 = 0; k0 < K; k0 += 64) {
#pragma unroll
    for (int c = 0; c < 4; ++c) {
      async_copy16(Ap[c] + k0, &As[(c * 256 + t) * 8]);
      async_copy16(Bp[c] + k0, &Bs[(c * 256 + t) * 8]);
    }
    __syncthreads();
#pragma unroll
    for (int half = 0; half < 2; ++half) {
      const bf16_t* Ash = &As[half * 4096];
      const bf16_t* Bsh = &Bs[half * 4096];
      bf16x8 af[4], bfr[4];
#pragma unroll
      for (int i = 0; i < 4; ++i)
        af[i] = *(const bf16x8*)&Ash[(wm + i * 16 + lr) * 32 + lq * 8];
#pragma unroll
      for (int j = 0; j < 4; ++j)
        bfr[j] = *(const bf16x8*)&Bsh[(wn + j * 16 + lr) * 32 + lq * 8];
#pragma unroll
      for (int i = 0; i < 4; ++i)
#pragma unroll
        for (int j = 0; j < 4; ++j)
          acc[i][j] = MFMA16(af[i], bfr[j], acc[i][j]);
    }
    __syncthreads();
  }
#pragma unroll
  for (int i = 0; i < 4; ++i) {
    const int row = bm + wm + i * 16 + lq * 4;
#pragma unroll
    for (int j = 0; j < 4; ++j) {
      const int col = bn + wn + j * 16 + lr;
#pragma unroll
      for (int r = 0; r < 4; ++r)
        Cb[(size_t)(row + r) * Nn + col] = (bf16_t)(acc[i][j][r] * osc);
    }
  }
}

// ---------------- flash attention v9: v8 + double-buffered K/V staging -------
// Single barrier per kt iteration: prefetch kt+1 into the alternate buffer
// right after the barrier; the vmcnt(0) drain at the next barrier waits on
// loads that had a full (long) compute phase in flight.
__global__ __launch_bounds__(256) void flash_attn(const bf16_t* __restrict__ q,
                                                  const bf16_t* __restrict__ k,
                                                  const bf16_t* __restrict__ vt,
                                                  bf16_t* __restrict__ Opart,
                                                  float* __restrict__ lpart) {
  constexpr int PSP = 72;
  __shared__ alignas(16) bf16_t Ks[2][64 * 64];
  __shared__ alignas(16) bf16_t Vs[2][64 * 64];
  __shared__ alignas(16) bf16_t Ps[4][32 * PSP];
  const int t = threadIdx.x;
  const int lane = t & 63;
  const int w = t >> 6;
  const int lr = lane & 15;
  const int lq = lane >> 4;
  const int qt = blockIdx.x;   // query tile 0..15 (128 wide)
  const int bh = blockIdx.y;   // b*16+h
  const int sp = blockIdx.z;   // key split 0..1
  const int b = bh >> 4;
  const int h = bh & 15;
  const size_t rowbase = (size_t)b * 2048;
  const int hcol = h * 64;
  const bf16_t* vtp = vt + (size_t)bh * 64 * 2048;

  bf16x8 qf[2][2];
#pragma unroll
  for (int u = 0; u < 2; ++u) {
    size_t qrow = rowbase + qt * 128 + w * 32 + u * 16 + lr;
    const bf16_t* qp = q + qrow * 1024 + hcol + lq * 8;
    qf[u][0] = *(const bf16x8*)qp;
    qf[u][1] = *(const bf16x8*)(qp + 32);
  }
  bf16x8 ones;
#pragma unroll
  for (int j = 0; j < 8; ++j) ones[j] = (bf16_t)1.0f;
  f32x4 of[2][4] = {};
  f32x4 ofl[2] = {};

  // staging lane geometry (shared by prologue + steady state)
  const int sr0 = t >> 3;             // row for rep=0 chunk set (cl = t)
  const int sc0 = (t & 7) ^ (sr0 & 7);
  const int sr1 = (256 + t) >> 3;     // row for rep=1 chunk set
  const int sc1 = (t & 7) ^ (sr1 & 7);

  const int kt0 = sp * 16;
  // prologue: stage kt0 into buffer 0
  {
    const size_t krow0 = rowbase + (size_t)kt0 * 64;
    async_copy16(k + (krow0 + sr0) * 1024 + hcol + sc0 * 8, &Ks[0][t * 8]);
    async_copy16(vtp + (size_t)sr0 * 2048 + kt0 * 64 + sc0 * 8, &Vs[0][t * 8]);
    async_copy16(k + (krow0 + sr1) * 1024 + hcol + sc1 * 8, &Ks[0][2048 + t * 8]);
    async_copy16(vtp + (size_t)sr1 * 2048 + kt0 * 64 + sc1 * 8, &Vs[0][2048 + t * 8]);
  }
  int buf = 0;
  for (int i = 0; i < 16; ++i) {
    __syncthreads();  // drains this buffer's loads; protects prev buffer reuse
    const int nb = buf ^ 1;
    if (i + 1 < 16) {
      const int ktn = kt0 + i + 1;
      const size_t krow0 = rowbase + (size_t)ktn * 64;
      async_copy16(k + (krow0 + sr0) * 1024 + hcol + sc0 * 8, &Ks[nb][t * 8]);
      async_copy16(vtp + (size_t)sr0 * 2048 + ktn * 64 + sc0 * 8, &Vs[nb][t * 8]);
      async_copy16(k + (krow0 + sr1) * 1024 + hcol + sc1 * 8, &Ks[nb][2048 + t * 8]);
      async_copy16(vtp + (size_t)sr1 * 2048 + ktn * 64 + sc1 * 8, &Vs[nb][2048 + t * 8]);
    }
    // S^T = K Q^T; kf reads shared across both q-subtiles
    f32x4 sc[2][4];
#pragma unroll
    for (int s = 0; s < 4; ++s) {
      const int r2 = s * 16 + lr;
      bf16x8 kf0 = *(const bf16x8*)&Ks[buf][r2 * 64 + ((lq) ^ (r2 & 7)) * 8];
      bf16x8 kf1 = *(const bf16x8*)&Ks[buf][r2 * 64 + ((4 + lq) ^ (r2 & 7)) * 8];
#pragma unroll
      for (int u = 0; u < 2; ++u) {
        f32x4 c = {};
        c = MFMA16(kf0, qf[u][0], c);
        c = MFMA16(kf1, qf[u][1], c);
        sc[u][s] = c;
      }
    }
    // p = exp2(dot) (Q pre-scaled); pack + store P^T (per-wave, no barrier)
#pragma unroll
    for (int u = 0; u < 2; ++u)
#pragma unroll
      for (int s = 0; s < 4; ++s) {
        bf16x4 pv;
#pragma unroll
        for (int r = 0; r < 4; ++r) pv[r] = (bf16_t)EXP2F(sc[u][s][r]);
        *(bf16x4*)&Ps[w][(u * 16 + lr) * PSP + s * 16 + lq * 4] = pv;
      }
    bf16x8 pf[2][2];
#pragma unroll
    for (int u = 0; u < 2; ++u) {
      pf[u][0] = *(const bf16x8*)&Ps[w][(u * 16 + lr) * PSP + lq * 8];
      pf[u][1] = *(const bf16x8*)&Ps[w][(u * 16 + lr) * PSP + 32 + lq * 8];
      ofl[u] = MFMA16(pf[u][0], ones, ofl[u]);
      ofl[u] = MFMA16(pf[u][1], ones, ofl[u]);
    }
    // O += P V  (vf reads shared across both subtiles)
#pragma unroll
    for (int d = 0; d < 4; ++d) {
      const int rv = d * 16 + lr;
      bf16x8 vf0 = *(const bf16x8*)&Vs[buf][rv * 64 + ((lq) ^ (rv & 7)) * 8];
      bf16x8 vf1 = *(const bf16x8*)&Vs[buf][rv * 64 + ((4 + lq) ^ (rv & 7)) * 8];
#pragma unroll
      for (int u = 0; u < 2; ++u) {
        of[u][d] = MFMA16(pf[u][0], vf0, of[u][d]);
        of[u][d] = MFMA16(pf[u][1], vf1, of[u][d]);
      }
    }
    buf = nb;
  }
  bf16_t* Op = Opart + (size_t)sp * 4096 * 1024;
  float* lp = lpart + (size_t)sp * 4096 * 16;
#pragma unroll
  for (int u = 0; u < 2; ++u) {
    const size_t grow0 = rowbase + qt * 128 + w * 32 + u * 16 + lq * 4;
#pragma unroll
    for (int r = 0; r < 4; ++r) {
#pragma unroll
      for (int d = 0; d < 4; ++d)
        Op[(grow0 + r) * 1024 + hcol + d * 16 + lr] = (bf16_t)of[u][d][r];
      if (lr == 0) lp[(grow0 + r) * 16 + h] = ofl[u][r];
    }
  }
}

// ---------------- split-K combine: attn = (O0+O1)/(l0+l1) --------------------
__global__ __launch_bounds__(256) void combine_k(const bf16_t* __restrict__ Opart,
                                                 const float* __restrict__ lpart,
                                                 bf16_t* __restrict__ attn) {
  const size_t row = blockIdx.x;
  const int t = threadIdx.x;
  const int h = t >> 4;
  const float inv =
      1.0f / (lpart[row * 16 + h] + lpart[4096 * 16 + row * 16 + h]);
  const size_t i = row * 1024 + t * 4;
  bf16x4 a = *(const bf16x4*)&Opart[i];
  bf16x4 bvv = *(const bf16x4*)&Opart[(size_t)4096 * 1024 + i];
  bf16x4 o;
#pragma unroll
  for (int j = 0; j < 4; ++j) o[j] = (bf16_t)(((float)a[j] + (float)bvv[j]) * inv);
  *(bf16x4*)&attn[i] = o;
}

extern "C" void kernel_launch(void* const* d_in, const int* in_sizes, int n_in,
                              void* d_out, int out_size, void* d_ws, size_t ws_size,
                              hipStream_t stream) {
  (void)in_sizes;
  (void)n_in;
  (void)out_size;
  (void)ws_size;
  const float* x = (const float*)d_in[0];
  const float* la1g = (const float*)d_in[1];
  const float* la1b = (const float*)d_in[2];
  const float* Wq = (const float*)d_in[3];
  const float* Wk = (const float*)d_in[4];
  const float* Wv = (const float*)d_in[5];
  const float* Wo = (const float*)d_in[6];
  const float* bo = (const float*)d_in[7];
  const float* la2g = (const float*)d_in[8];
  const float* la2b = (const float*)d_in[9];
  const float* W1 = (const float*)d_in[10];
  const float* b1 = (const float*)d_in[11];
  const float* W2 = (const float*)d_in[12];
  const float* b2 = (const float*)d_in[13];
  char* ws = (char*)d_ws;
  const size_t MB = (size_t)1 << 20;
  bf16_t* wq_b = (bf16_t*)(ws + 0 * MB);
  bf16_t* wk_b = (bf16_t*)(ws + 2 * MB);
  bf16_t* wv_b = (bf16_t*)(ws + 4 * MB);
  bf16_t* wo_b = (bf16_t*)(ws + 6 * MB);
  bf16_t* w1_b = (bf16_t*)(ws + 8 * MB);
  bf16_t* w2_b = (bf16_t*)(ws + 16 * MB);
  bf16_t* hbuf = (bf16_t*)(ws + 24 * MB);  // reused as vt after QKV
  bf16_t* qb = (bf16_t*)(ws + 32 * MB);
  bf16_t* kb = (bf16_t*)(ws + 40 * MB);
  bf16_t* vb = (bf16_t*)(ws + 48 * MB);
  bf16_t* attn = (bf16_t*)(ws + 56 * MB);
  float* outb = (float*)(ws + 64 * MB);      // 16 MB fp32
  bf16_t* h2 = (bf16_t*)(ws + 80 * MB);      // 8 MB
  bf16_t* m1 = (bf16_t*)(ws + 88 * MB);      // 32 MB (88-120)
  bf16_t* vt = hbuf;
  // flash split-K scratch (dead after combine): overlays outb/h2 slots
  bf16_t* Opart = (bf16_t*)(ws + 64 * MB);   // 2 x 8 MB bf16
  float* lpart = (float*)(ws + 80 * MB);     // 512 KB fp32
  // W2 split-K partials: overlay slots dead after flash (vt 24-32, qb 32-48)
  float* p0 = (float*)(ws + 24 * MB);        // 16 MB fp32 (24-40)
  float* p1 = (float*)(ws + 40 * MB);        // 16 MB fp32 (40-56)
  float* dout = (float*)d_out;

  cvt4_k<<<dim3(1024, 4), 256, 0, stream>>>(Wq, Wk, Wv, Wo, wq_b, wk_b, wv_b, wo_b);
  cvt2_k<<<dim3(4096, 2), 256, 0, stream>>>(W1, W2, w1_b, w2_b);
  ln_k<<<4096, 256, 0, stream>>>(x, la1g, la1b, hbuf);
  gemm_qkv<<<dim3(8, 32, 3), 256, 0, stream>>>(hbuf, wq_b, wk_b, wv_b, qb, kb, vb);
  vtrans_k<<<dim3(32, 32), 256, 0, stream>>>(vb, vt);
  flash_attn<<<dim3(16, 32, 2), 256, 0, stream>>>(qb, kb, vt, Opart, lpart);
  combine_k<<<4096, 256, 0, stream>>>(Opart, lpart, attn);
  gemm64_bt<1><<<dim3(8, 64), 256, 0, stream>>>(attn, wo_b, outb, bo, x, 4096, 1024, 1024);
  ln_k<<<4096, 256, 0, stream>>>(outb, la2g, la2b, h2);
  gemm_bt<2><<<dim3(32, 32), 256, 0, stream>>>(h2, w1_b, nullptr, m1, b1, nullptr, 4096, 4096, 1024);
  gemm_sk<<<dim3(8, 32, 2), 256, 0, stream>>>(m1, w2_b, p0, p1);
  w2_epi<<<4096, 256, 0, stream>>>(p0, p1, b2, outb, dout);
}

// Round 13
// 353.801 us; speedup vs baseline: 1.0362x; 1.0351x over previous
//
#include <hip/hip_runtime.h>
#include <hip/hip_bf16.h>

typedef __bf16 bf16_t;
typedef __bf16 bf16x4 __attribute__((ext_vector_type(4)));
typedef __bf16 bf16x8 __attribute__((ext_vector_type(8)));
typedef float f32x4 __attribute__((ext_vector_type(4)));

#define MFMA16(a, b, c) __builtin_amdgcn_mfma_f32_16x16x32_bf16((a), (b), (c), 0, 0, 0)

#if defined(__has_builtin) && __has_builtin(__builtin_amdgcn_exp2f)
#define EXP2F(x) __builtin_amdgcn_exp2f(x)
#else
#define EXP2F(x) exp2f(x)
#endif

__device__ __forceinline__ void async_copy16(const void* g, void* l) {
#if defined(__has_builtin) && __has_builtin(__builtin_amdgcn_global_load_lds)
  __builtin_amdgcn_global_load_lds((__attribute__((address_space(1))) void*)g,
                                   (__attribute__((address_space(3))) void*)l, 16, 0, 0);
#else
  *(bf16x8*)l = *(const bf16x8*)g;
#endif
}

// tanh-approx GELU in sigmoid form: x*sigmoid(2c(x+0.044715x^3)); |err|<~3e-3
__device__ __forceinline__ float gelu_f(float x) {
  float u = x * (1.5957691216057308f + 0.07135481283f * x * x);
  return x / (1.0f + __expf(-u));
}

// ---------------- weight fp32 -> bf16 converts (merged dispatches) -----------
__global__ __launch_bounds__(256) void cvt4_k(const float* __restrict__ s0,
                                              const float* __restrict__ s1,
                                              const float* __restrict__ s2,
                                              const float* __restrict__ s3,
                                              bf16_t* __restrict__ d0,
                                              bf16_t* __restrict__ d1,
                                              bf16_t* __restrict__ d2,
                                              bf16_t* __restrict__ d3) {
  const int y = blockIdx.y;
  const float* s = (y == 0) ? s0 : (y == 1) ? s1 : (y == 2) ? s2 : s3;
  bf16_t* d = (y == 0) ? d0 : (y == 1) ? d1 : (y == 2) ? d2 : d3;
  int i = (blockIdx.x * 256 + threadIdx.x) * 4;
  float4 f = *(const float4*)(s + i);
  d[i + 0] = (bf16_t)f.x;
  d[i + 1] = (bf16_t)f.y;
  d[i + 2] = (bf16_t)f.z;
  d[i + 3] = (bf16_t)f.w;
}

__global__ __launch_bounds__(256) void cvt2_k(const float* __restrict__ s0,
                                              const float* __restrict__ s1,
                                              bf16_t* __restrict__ d0,
                                              bf16_t* __restrict__ d1) {
  const int y = blockIdx.y;
  const float* s = (y == 0) ? s0 : s1;
  bf16_t* d = (y == 0) ? d0 : d1;
  int i = (blockIdx.x * 256 + threadIdx.x) * 4;
  float4 f = *(const float4*)(s + i);
  d[i + 0] = (bf16_t)f.x;
  d[i + 1] = (bf16_t)f.y;
  d[i + 2] = (bf16_t)f.z;
  d[i + 3] = (bf16_t)f.w;
}

// ---------------- layernorm over 1024 cols, one block per row ----------------
__global__ __launch_bounds__(256) void ln_k(const float* __restrict__ x,
                                            const float* __restrict__ g,
                                            const float* __restrict__ b,
                                            bf16_t* __restrict__ o) {
  __shared__ float red[8];
  const int t = threadIdx.x;
  const size_t row = blockIdx.x;
  float4 xv = ((const float4*)(x + row * 1024))[t];
  float s = xv.x + xv.y + xv.z + xv.w;
  float s2 = xv.x * xv.x + xv.y * xv.y + xv.z * xv.z + xv.w * xv.w;
#pragma unroll
  for (int off = 1; off < 64; off <<= 1) {
    s += __shfl_xor(s, off);
    s2 += __shfl_xor(s2, off);
  }
  if ((t & 63) == 0) {
    red[t >> 6] = s;
    red[4 + (t >> 6)] = s2;
  }
  __syncthreads();
  s = red[0] + red[1] + red[2] + red[3];
  s2 = red[4] + red[5] + red[6] + red[7];
  const float mu = s * (1.0f / 1024.0f);
  const float rstd = rsqrtf(s2 * (1.0f / 1024.0f) - mu * mu + 1e-5f);
  float4 gv = ((const float4*)g)[t];
  float4 bv = ((const float4*)b)[t];
  bf16_t* op = o + row * 1024 + t * 4;
  op[0] = (bf16_t)((xv.x - mu) * rstd * gv.x + bv.x);
  op[1] = (bf16_t)((xv.y - mu) * rstd * gv.y + bv.y);
  op[2] = (bf16_t)((xv.z - mu) * rstd * gv.z + bv.z);
  op[3] = (bf16_t)((xv.w - mu) * rstd * gv.w + bv.w);
}

// ---------------- 128x128xBK64 GEMM: C = A[M,K] @ W[Nn,K]^T ------------------
template <int EPI>
__global__ __launch_bounds__(256, 4) void gemm_bt(const bf16_t* __restrict__ A,
                                                  const bf16_t* __restrict__ W,
                                                  float* __restrict__ Cf,
                                                  bf16_t* __restrict__ Cb,
                                                  const float* __restrict__ bias,
                                                  const float* __restrict__ resid,
                                                  int M, int Nn, int K) {
  __shared__ alignas(16) bf16_t As[2 * 128 * 32];
  __shared__ alignas(16) bf16_t Bs[2 * 128 * 32];
  const int t = threadIdx.x;
  const int lane = t & 63;
  const int w = t >> 6;
  const int bm = blockIdx.y * 128;
  const int bn = blockIdx.x * 128;
  const int wm = (w >> 1) * 64;
  const int wn = (w & 1) * 64;
  const int lr = lane & 15;
  const int lq = lane >> 4;
  f32x4 acc[4][4] = {};
  const bf16_t* Ap[4];
  const bf16_t* Bp[4];
#pragma unroll
  for (int c = 0; c < 4; ++c) {
    const int flat = c * 256 + t;
    const int p = flat >> 9;
    const int r = (flat >> 2) & 127;
    const int q = flat & 3;
    Ap[c] = A + (size_t)(bm + r) * K + p * 32 + q * 8;
    Bp[c] = W + (size_t)(bn + r) * K + p * 32 + q * 8;
  }
  for (int k0 = 0; k0 < K; k0 += 64) {
#pragma unroll
    for (int c = 0; c < 4; ++c) {
      async_copy16(Ap[c] + k0, &As[(c * 256 + t) * 8]);
      async_copy16(Bp[c] + k0, &Bs[(c * 256 + t) * 8]);
    }
    __syncthreads();
#pragma unroll
    for (int half = 0; half < 2; ++half) {
      const bf16_t* Ash = &As[half * 4096];
      const bf16_t* Bsh = &Bs[half * 4096];
      bf16x8 af[4], bfr[4];
#pragma unroll
      for (int i = 0; i < 4; ++i)
        af[i] = *(const bf16x8*)&Ash[(wm + i * 16 + lr) * 32 + lq * 8];
#pragma unroll
      for (int j = 0; j < 4; ++j)
        bfr[j] = *(const bf16x8*)&Bsh[(wn + j * 16 + lr) * 32 + lq * 8];
#pragma unroll
      for (int i = 0; i < 4; ++i)
#pragma unroll
        for (int j = 0; j < 4; ++j)
          acc[i][j] = MFMA16(af[i], bfr[j], acc[i][j]);
    }
    __syncthreads();
  }
#pragma unroll
  for (int i = 0; i < 4; ++i) {
    const int row = bm + wm + i * 16 + lq * 4;
#pragma unroll
    for (int j = 0; j < 4; ++j) {
      const int col = bn + wn + j * 16 + lr;
      float bcol = (EPI >= 1) ? bias[col] : 0.0f;
#pragma unroll
      for (int r = 0; r < 4; ++r) {
        size_t idx = (size_t)(row + r) * Nn + col;
        float vv = acc[i][j][r];
        if (EPI == 0) {
          Cb[idx] = (bf16_t)vv;
        } else if (EPI == 1) {
          Cf[idx] = vv + bcol + resid[idx];
        } else if (EPI == 2) {
          Cb[idx] = (bf16_t)gelu_f(vv + bcol);
        } else {
          Cf[idx] = gelu_f(vv + bcol) + resid[idx];
        }
      }
    }
  }
}

// ---------------- split-K 128x128 GEMM: fp32 partials, dbuf, XCD swizzle -----
// XCD owns a 4-wide bm stripe, iterates bn fastest -> A row-chunk reused 8x
// in its L2 (A refetch x1 + B x8 ~ 80 MB vs ~136 MB unswizzled).
__global__ __launch_bounds__(256, 2) void gemm_sk(const bf16_t* __restrict__ A,
                                                  const bf16_t* __restrict__ W,
                                                  float* __restrict__ P0,
                                                  float* __restrict__ P1) {
  const int K = 4096, Nn = 1024;
  __shared__ alignas(16) bf16_t As[2][128 * 64];
  __shared__ alignas(16) bf16_t Bs[2][128 * 64];
  const int t = threadIdx.x;
  const int lane = t & 63;
  const int w = t >> 6;
  const int lin = blockIdx.x + 8 * blockIdx.y;  // 0..255
  const int bm = ((lin & 7) * 4 + ((lin >> 6) & 3)) * 128;
  const int bn = ((lin >> 3) & 7) * 128;
  const int sp = blockIdx.z;
  float* Cf = sp ? P1 : P0;
  const int kbase = sp * 2048;
  const int wm = (w >> 1) * 64;
  const int wn = (w & 1) * 64;
  const int lr = lane & 15;
  const int lq = lane >> 4;
  f32x4 acc[4][4] = {};
  const bf16_t* Ap[4];
  const bf16_t* Bp[4];
#pragma unroll
  for (int c = 0; c < 4; ++c) {
    const int flat = c * 256 + t;
    const int p = flat >> 9;
    const int r = (flat >> 2) & 127;
    const int q = flat & 3;
    Ap[c] = A + (size_t)(bm + r) * K + kbase + p * 32 + q * 8;
    Bp[c] = W + (size_t)(bn + r) * K + kbase + p * 32 + q * 8;
  }
#pragma unroll
  for (int c = 0; c < 4; ++c) {
    async_copy16(Ap[c], &As[0][(c * 256 + t) * 8]);
    async_copy16(Bp[c], &Bs[0][(c * 256 + t) * 8]);
  }
  int buf = 0;
  for (int k0 = 0; k0 < 2048; k0 += 64) {
    __syncthreads();
    const int nb = buf ^ 1;
    if (k0 + 64 < 2048) {
#pragma unroll
      for (int c = 0; c < 4; ++c) {
        async_copy16(Ap[c] + k0 + 64, &As[nb][(c * 256 + t) * 8]);
        async_copy16(Bp[c] + k0 + 64, &Bs[nb][(c * 256 + t) * 8]);
      }
    }
#pragma unroll
    for (int half = 0; half < 2; ++half) {
      const bf16_t* Ash = &As[buf][half * 4096];
      const bf16_t* Bsh = &Bs[buf][half * 4096];
      bf16x8 af[4], bfr[4];
#pragma unroll
      for (int i = 0; i < 4; ++i)
        af[i] = *(const bf16x8*)&Ash[(wm + i * 16 + lr) * 32 + lq * 8];
#pragma unroll
      for (int j = 0; j < 4; ++j)
        bfr[j] = *(const bf16x8*)&Bsh[(wn + j * 16 + lr) * 32 + lq * 8];
#pragma unroll
      for (int i = 0; i < 4; ++i)
#pragma unroll
        for (int j = 0; j < 4; ++j)
          acc[i][j] = MFMA16(af[i], bfr[j], acc[i][j]);
    }
    buf = nb;
  }
#pragma unroll
  for (int i = 0; i < 4; ++i) {
    const int row = bm + wm + i * 16 + lq * 4;
#pragma unroll
    for (int j = 0; j < 4; ++j) {
      const int col = bn + wn + j * 16 + lr;
#pragma unroll
      for (int r = 0; r < 4; ++r)
        Cf[(size_t)(row + r) * Nn + col] = acc[i][j][r];
    }
  }
}

// ---------------- W2 epilogue: dout = gelu(p0+p1+bias) + resid ---------------
__global__ __launch_bounds__(256) void w2_epi(const float* __restrict__ P0,
                                              const float* __restrict__ P1,
                                              const float* __restrict__ bias,
                                              const float* __restrict__ resid,
                                              float* __restrict__ dout) {
  const size_t i = ((size_t)blockIdx.x * 256 + threadIdx.x) * 4;
  const int col = threadIdx.x * 4;
  float4 p0 = *(const float4*)(P0 + i);
  float4 p1 = *(const float4*)(P1 + i);
  float4 bv = *(const float4*)(bias + col);
  float4 rv = *(const float4*)(resid + i);
  float4 o;
  o.x = gelu_f(p0.x + p1.x + bv.x) + rv.x;
  o.y = gelu_f(p0.y + p1.y + bv.y) + rv.y;
  o.z = gelu_f(p0.z + p1.z + bv.z) + rv.z;
  o.w = gelu_f(p0.w + p1.w + bv.w) + rv.w;
  *(float4*)(dout + i) = o;
}

// ---------------- 64x128xBK64 GEMM, dbuf + XCD-locality swizzle --------------
template <int EPI>
__global__ __launch_bounds__(256, 4) void gemm64_bt(const bf16_t* __restrict__ A,
                                                    const bf16_t* __restrict__ W,
                                                    float* __restrict__ Cf,
                                                    const float* __restrict__ bias,
                                                    const float* __restrict__ resid,
                                                    int M, int Nn, int K) {
  __shared__ alignas(16) bf16_t As[2][2 * 64 * 32];
  __shared__ alignas(16) bf16_t Bs[2][2 * 128 * 32];
  const int t = threadIdx.x;
  const int lane = t & 63;
  const int w = t >> 6;
  const int lin = blockIdx.x + 8 * blockIdx.y;
  const int bm = ((lin & 7) * 8 + (lin >> 6)) * 64;
  const int bn = ((lin >> 3) & 7) * 128;
  const int wm = (w >> 1) * 32;
  const int wn = (w & 1) * 64;
  const int lr = lane & 15;
  const int lq = lane >> 4;
  f32x4 acc[2][4] = {};
  const bf16_t* Ap[2];
  const bf16_t* Bp[4];
#pragma unroll
  for (int c = 0; c < 2; ++c) {
    const int flat = c * 256 + t;
    const int p = flat >> 8;
    const int r = (flat >> 2) & 63;
    const int q = flat & 3;
    Ap[c] = A + (size_t)(bm + r) * K + p * 32 + q * 8;
  }
#pragma unroll
  for (int c = 0; c < 4; ++c) {
    const int flat = c * 256 + t;
    const int p = flat >> 9;
    const int r = (flat >> 2) & 127;
    const int q = flat & 3;
    Bp[c] = W + (size_t)(bn + r) * K + p * 32 + q * 8;
  }
#pragma unroll
  for (int c = 0; c < 2; ++c) async_copy16(Ap[c], &As[0][(c * 256 + t) * 8]);
#pragma unroll
  for (int c = 0; c < 4; ++c) async_copy16(Bp[c], &Bs[0][(c * 256 + t) * 8]);
  int buf = 0;
  for (int k0 = 0; k0 < K; k0 += 64) {
    __syncthreads();
    const int nb = buf ^ 1;
    if (k0 + 64 < K) {
#pragma unroll
      for (int c = 0; c < 2; ++c)
        async_copy16(Ap[c] + k0 + 64, &As[nb][(c * 256 + t) * 8]);
#pragma unroll
      for (int c = 0; c < 4; ++c)
        async_copy16(Bp[c] + k0 + 64, &Bs[nb][(c * 256 + t) * 8]);
    }
#pragma unroll
    for (int half = 0; half < 2; ++half) {
      const bf16_t* Ash = &As[buf][half * 2048];
      const bf16_t* Bsh = &Bs[buf][half * 4096];
      bf16x8 af[2], bfr[4];
#pragma unroll
      for (int i = 0; i < 2; ++i)
        af[i] = *(const bf16x8*)&Ash[(wm + i * 16 + lr) * 32 + lq * 8];
#pragma unroll
      for (int j = 0; j < 4; ++j)
        bfr[j] = *(const bf16x8*)&Bsh[(wn + j * 16 + lr) * 32 + lq * 8];
#pragma unroll
      for (int i = 0; i < 2; ++i)
#pragma unroll
        for (int j = 0; j < 4; ++j)
          acc[i][j] = MFMA16(af[i], bfr[j], acc[i][j]);
    }
    buf = nb;
  }
#pragma unroll
  for (int i = 0; i < 2; ++i) {
    const int row = bm + wm + i * 16 + lq * 4;
#pragma unroll
    for (int j = 0; j < 4; ++j) {
      const int col = bn + wn + j * 16 + lr;
      float bcol = bias[col];
#pragma unroll
      for (int r = 0; r < 4; ++r) {
        size_t idx = (size_t)(row + r) * Nn + col;
        float vv = acc[i][j][r];
        if (EPI == 1)
          Cf[idx] = vv + bcol + resid[idx];
        else
          Cf[idx] = gelu_f(vv + bcol) + resid[idx];
      }
    }
  }
}

// ---------------- fused QKV GEMM (BK=64); Q pre-scaled, V written transposed -
// z==0: Q * log2(e)/32 -> qb ; z==1: K -> kb ;
// z==2: V written directly in vt layout [b*16+h][64 d][2048 n] (C-layout reg
// quad = 4 consecutive n at fixed d -> aligned b64 stores). Kills vtrans_k.
__global__ __launch_bounds__(256) void gemm_qkv(const bf16_t* __restrict__ A,
                                                const bf16_t* __restrict__ W0,
                                                const bf16_t* __restrict__ W1,
                                                const bf16_t* __restrict__ W2,
                                                bf16_t* __restrict__ C0,
                                                bf16_t* __restrict__ C1,
                                                bf16_t* __restrict__ vt) {
  const int z = blockIdx.z;
  const bf16_t* W = (z == 0) ? W0 : ((z == 1) ? W1 : W2);
  const float osc = (z == 0) ? 0.045084220027780106f : 1.0f;
  const int K = 1024, Nn = 1024;
  __shared__ alignas(16) bf16_t As[2 * 128 * 32];
  __shared__ alignas(16) bf16_t Bs[2 * 128 * 32];
  const int t = threadIdx.x;
  const int lane = t & 63;
  const int w = t >> 6;
  const int bm = blockIdx.y * 128;
  const int bn = blockIdx.x * 128;
  const int wm = (w >> 1) * 64;
  const int wn = (w & 1) * 64;
  const int lr = lane & 15;
  const int lq = lane >> 4;
  f32x4 acc[4][4] = {};
  const bf16_t* Ap[4];
  const bf16_t* Bp[4];
#pragma unroll
  for (int c = 0; c < 4; ++c) {
    const int flat = c * 256 + t;
    const int p = flat >> 9;
    const int r = (flat >> 2) & 127;
    const int q = flat & 3;
    Ap[c] = A + (size_t)(bm + r) * K + p * 32 + q * 8;
    Bp[c] = W + (size_t)(bn + r) * K + p * 32 + q * 8;
  }
  for (int k0 = 0; k0 < K; k0 += 64) {
#pragma unroll
    for (int c = 0; c < 4; ++c) {
      async_copy16(Ap[c] + k0, &As[(c * 256 + t) * 8]);
      async_copy16(Bp[c] + k0, &Bs[(c * 256 + t) * 8]);
    }
    __syncthreads();
#pragma unroll
    for (int half = 0; half < 2; ++half) {
      const bf16_t* Ash = &As[half * 4096];
      const bf16_t* Bsh = &Bs[half * 4096];
      bf16x8 af[4], bfr[4];
#pragma unroll
      for (int i = 0; i < 4; ++i)
        af[i] = *(const bf16x8*)&Ash[(wm + i * 16 + lr) * 32 + lq * 8];
#pragma unroll
      for (int j = 0; j < 4; ++j)
        bfr[j] = *(const bf16x8*)&Bsh[(wn + j * 16 + lr) * 32 + lq * 8];
#pragma unroll
      for (int i = 0; i < 4; ++i)
#pragma unroll
        for (int j = 0; j < 4; ++j)
          acc[i][j] = MFMA16(af[i], bfr[j], acc[i][j]);
    }
    __syncthreads();
  }
  if (z == 2) {
    // V transposed: vt[((b*16 + col/64)*64 + col%64)*2048 + n], quad = 4 n's
#pragma unroll
    for (int i = 0; i < 4; ++i) {
      const int row0 = bm + wm + i * 16 + lq * 4;  // n index base
      const int b = row0 >> 11;
      const int n = row0 & 2047;
#pragma unroll
      for (int j = 0; j < 4; ++j) {
        const int col = bn + wn + j * 16 + lr;  // global d (h*64 + dloc)
        bf16x4 pv;
#pragma unroll
        for (int r = 0; r < 4; ++r) pv[r] = (bf16_t)acc[i][j][r];
        *(bf16x4*)&vt[((size_t)(b * 16 + (col >> 6)) * 64 + (col & 63)) * 2048 + n] = pv;
      }
    }
  } else {
    bf16_t* Cb = (z == 0) ? C0 : C1;
#pragma unroll
    for (int i = 0; i < 4; ++i) {
      const int row = bm + wm + i * 16 + lq * 4;
#pragma unroll
      for (int j = 0; j < 4; ++j) {
        const int col = bn + wn + j * 16 + lr;
#pragma unroll
        for (int r = 0; r < 4; ++r)
          Cb[(size_t)(row + r) * Nn + col] = (bf16_t)(acc[i][j][r] * osc);
      }
    }
  }
}

// ---------------- flash attention v9: 128q + split-K + dbuf K/V --------------
__global__ __launch_bounds__(256) void flash_attn(const bf16_t* __restrict__ q,
                                                  const bf16_t* __restrict__ k,
                                                  const bf16_t* __restrict__ vt,
                                                  bf16_t* __restrict__ Opart,
                                                  float* __restrict__ lpart) {
  constexpr int PSP = 72;
  __shared__ alignas(16) bf16_t Ks[2][64 * 64];
  __shared__ alignas(16) bf16_t Vs[2][64 * 64];
  __shared__ alignas(16) bf16_t Ps[4][32 * PSP];
  const int t = threadIdx.x;
  const int lane = t & 63;
  const int w = t >> 6;
  const int lr = lane & 15;
  const int lq = lane >> 4;
  const int qt = blockIdx.x;   // query tile 0..15 (128 wide)
  const int bh = blockIdx.y;   // b*16+h
  const int sp = blockIdx.z;   // key split 0..1
  const int b = bh >> 4;
  const int h = bh & 15;
  const size_t rowbase = (size_t)b * 2048;
  const int hcol = h * 64;
  const bf16_t* vtp = vt + (size_t)bh * 64 * 2048;

  bf16x8 qf[2][2];
#pragma unroll
  for (int u = 0; u < 2; ++u) {
    size_t qrow = rowbase + qt * 128 + w * 32 + u * 16 + lr;
    const bf16_t* qp = q + qrow * 1024 + hcol + lq * 8;
    qf[u][0] = *(const bf16x8*)qp;
    qf[u][1] = *(const bf16x8*)(qp + 32);
  }
  bf16x8 ones;
#pragma unroll
  for (int j = 0; j < 8; ++j) ones[j] = (bf16_t)1.0f;
  f32x4 of[2][4] = {};
  f32x4 ofl[2] = {};

  const int sr0 = t >> 3;
  const int sc0 = (t & 7) ^ (sr0 & 7);
  const int sr1 = (256 + t) >> 3;
  const int sc1 = (t & 7) ^ (sr1 & 7);

  const int kt0 = sp * 16;
  {
    const size_t krow0 = rowbase + (size_t)kt0 * 64;
    async_copy16(k + (krow0 + sr0) * 1024 + hcol + sc0 * 8, &Ks[0][t * 8]);
    async_copy16(vtp + (size_t)sr0 * 2048 + kt0 * 64 + sc0 * 8, &Vs[0][t * 8]);
    async_copy16(k + (krow0 + sr1) * 1024 + hcol + sc1 * 8, &Ks[0][2048 + t * 8]);
    async_copy16(vtp + (size_t)sr1 * 2048 + kt0 * 64 + sc1 * 8, &Vs[0][2048 + t * 8]);
  }
  int buf = 0;
  for (int i = 0; i < 16; ++i) {
    __syncthreads();
    const int nb = buf ^ 1;
    if (i + 1 < 16) {
      const int ktn = kt0 + i + 1;
      const size_t krow0 = rowbase + (size_t)ktn * 64;
      async_copy16(k + (krow0 + sr0) * 1024 + hcol + sc0 * 8, &Ks[nb][t * 8]);
      async_copy16(vtp + (size_t)sr0 * 2048 + ktn * 64 + sc0 * 8, &Vs[nb][t * 8]);
      async_copy16(k + (krow0 + sr1) * 1024 + hcol + sc1 * 8, &Ks[nb][2048 + t * 8]);
      async_copy16(vtp + (size_t)sr1 * 2048 + ktn * 64 + sc1 * 8, &Vs[nb][2048 + t * 8]);
    }
    f32x4 sc[2][4];
#pragma unroll
    for (int s = 0; s < 4; ++s) {
      const int r2 = s * 16 + lr;
      bf16x8 kf0 = *(const bf16x8*)&Ks[buf][r2 * 64 + ((lq) ^ (r2 & 7)) * 8];
      bf16x8 kf1 = *(const bf16x8*)&Ks[buf][r2 * 64 + ((4 + lq) ^ (r2 & 7)) * 8];
#pragma unroll
      for (int u = 0; u < 2; ++u) {
        f32x4 c = {};
        c = MFMA16(kf0, qf[u][0], c);
        c = MFMA16(kf1, qf[u][1], c);
        sc[u][s] = c;
      }
    }
#pragma unroll
    for (int u = 0; u < 2; ++u)
#pragma unroll
      for (int s = 0; s < 4; ++s) {
        bf16x4 pv;
#pragma unroll
        for (int r = 0; r < 4; ++r) pv[r] = (bf16_t)EXP2F(sc[u][s][r]);
        *(bf16x4*)&Ps[w][(u * 16 + lr) * PSP + s * 16 + lq * 4] = pv;
      }
    bf16x8 pf[2][2];
#pragma unroll
    for (int u = 0; u < 2; ++u) {
      pf[u][0] = *(const bf16x8*)&Ps[w][(u * 16 + lr) * PSP + lq * 8];
      pf[u][1] = *(const bf16x8*)&Ps[w][(u * 16 + lr) * PSP + 32 + lq * 8];
      ofl[u] = MFMA16(pf[u][0], ones, ofl[u]);
      ofl[u] = MFMA16(pf[u][1], ones, ofl[u]);
    }
#pragma unroll
    for (int d = 0; d < 4; ++d) {
      const int rv = d * 16 + lr;
      bf16x8 vf0 = *(const bf16x8*)&Vs[buf][rv * 64 + ((lq) ^ (rv & 7)) * 8];
      bf16x8 vf1 = *(const bf16x8*)&Vs[buf][rv * 64 + ((4 + lq) ^ (rv & 7)) * 8];
#pragma unroll
      for (int u = 0; u < 2; ++u) {
        of[u][d] = MFMA16(pf[u][0], vf0, of[u][d]);
        of[u][d] = MFMA16(pf[u][1], vf1, of[u][d]);
      }
    }
    buf = nb;
  }
  bf16_t* Op = Opart + (size_t)sp * 4096 * 1024;
  float* lp = lpart + (size_t)sp * 4096 * 16;
#pragma unroll
  for (int u = 0; u < 2; ++u) {
    const size_t grow0 = rowbase + qt * 128 + w * 32 + u * 16 + lq * 4;
#pragma unroll
    for (int r = 0; r < 4; ++r) {
#pragma unroll
      for (int d = 0; d < 4; ++d)
        Op[(grow0 + r) * 1024 + hcol + d * 16 + lr] = (bf16_t)of[u][d][r];
      if (lr == 0) lp[(grow0 + r) * 16 + h] = ofl[u][r];
    }
  }
}

// ---------------- split-K combine: attn = (O0+O1)/(l0+l1) --------------------
__global__ __launch_bounds__(256) void combine_k(const bf16_t* __restrict__ Opart,
                                                 const float* __restrict__ lpart,
                                                 bf16_t* __restrict__ attn) {
  const size_t row = blockIdx.x;
  const int t = threadIdx.x;
  const int h = t >> 4;
  const float inv =
      1.0f / (lpart[row * 16 + h] + lpart[4096 * 16 + row * 16 + h]);
  const size_t i = row * 1024 + t * 4;
  bf16x4 a = *(const bf16x4*)&Opart[i];
  bf16x4 bvv = *(const bf16x4*)&Opart[(size_t)4096 * 1024 + i];
  bf16x4 o;
#pragma unroll
  for (int j = 0; j < 4; ++j) o[j] = (bf16_t)(((float)a[j] + (float)bvv[j]) * inv);
  *(bf16x4*)&attn[i] = o;
}

extern "C" void kernel_launch(void* const* d_in, const int* in_sizes, int n_in,
                              void* d_out, int out_size, void* d_ws, size_t ws_size,
                              hipStream_t stream) {
  (void)in_sizes;
  (void)n_in;
  (void)out_size;
  (void)ws_size;
  const float* x = (const float*)d_in[0];
  const float* la1g = (const float*)d_in[1];
  const float* la1b = (const float*)d_in[2];
  const float* Wq = (const float*)d_in[3];
  const float* Wk = (const float*)d_in[4];
  const float* Wv = (const float*)d_in[5];
  const float* Wo = (const float*)d_in[6];
  const float* bo = (const float*)d_in[7];
  const float* la2g = (const float*)d_in[8];
  const float* la2b = (const float*)d_in[9];
  const float* W1 = (const float*)d_in[10];
  const float* b1 = (const float*)d_in[11];
  const float* W2 = (const float*)d_in[12];
  const float* b2 = (const float*)d_in[13];
  char* ws = (char*)d_ws;
  const size_t MB = (size_t)1 << 20;
  bf16_t* wq_b = (bf16_t*)(ws + 0 * MB);
  bf16_t* wk_b = (bf16_t*)(ws + 2 * MB);
  bf16_t* wv_b = (bf16_t*)(ws + 4 * MB);
  bf16_t* wo_b = (bf16_t*)(ws + 6 * MB);
  bf16_t* w1_b = (bf16_t*)(ws + 8 * MB);
  bf16_t* w2_b = (bf16_t*)(ws + 16 * MB);
  bf16_t* hbuf = (bf16_t*)(ws + 24 * MB);  // ln1 out, QKV input
  bf16_t* qb = (bf16_t*)(ws + 32 * MB);
  bf16_t* kb = (bf16_t*)(ws + 40 * MB);
  bf16_t* vt = (bf16_t*)(ws + 48 * MB);    // V written transposed by QKV
  bf16_t* attn = (bf16_t*)(ws + 56 * MB);
  float* outb = (float*)(ws + 64 * MB);    // 16 MB fp32
  bf16_t* h2 = (bf16_t*)(ws + 80 * MB);    // 8 MB
  bf16_t* m1 = (bf16_t*)(ws + 88 * MB);    // 32 MB (88-120)
  // flash split-K scratch (dead after combine): overlays outb/h2 slots
  bf16_t* Opart = (bf16_t*)(ws + 64 * MB); // 2 x 8 MB bf16
  float* lpart = (float*)(ws + 80 * MB);   // 512 KB fp32
  // W2 split-K partials: overlay slots dead after flash (hbuf/qb, kb/vt)
  float* p0 = (float*)(ws + 24 * MB);      // 16 MB fp32 (24-40)
  float* p1 = (float*)(ws + 40 * MB);      // 16 MB fp32 (40-56)
  float* dout = (float*)d_out;

  cvt4_k<<<dim3(1024, 4), 256, 0, stream>>>(Wq, Wk, Wv, Wo, wq_b, wk_b, wv_b, wo_b);
  cvt2_k<<<dim3(4096, 2), 256, 0, stream>>>(W1, W2, w1_b, w2_b);
  ln_k<<<4096, 256, 0, stream>>>(x, la1g, la1b, hbuf);
  gemm_qkv<<<dim3(8, 32, 3), 256, 0, stream>>>(hbuf, wq_b, wk_b, wv_b, qb, kb, vt);
  flash_attn<<<dim3(16, 32, 2), 256, 0, stream>>>(qb, kb, vt, Opart, lpart);
  combine_k<<<4096, 256, 0, stream>>>(Opart, lpart, attn);
  gemm64_bt<1><<<dim3(8, 64), 256, 0, stream>>>(attn, wo_b, outb, bo, x, 4096, 1024, 1024);
  ln_k<<<4096, 256, 0, stream>>>(outb, la2g, la2b, h2);
  gemm_bt<2><<<dim3(32, 32), 256, 0, stream>>>(h2, w1_b, nullptr, m1, b1, nullptr, 4096, 4096, 1024);
  gemm_sk<<<dim3(8, 32, 2), 256, 0, stream>>>(m1, w2_b, p0, p1);
  w2_epi<<<4096, 256, 0, stream>>>(p0, p1, b2, outb, dout);
}

// Round 14
// 345.052 us; speedup vs baseline: 1.0625x; 1.0254x over previous
//
#include <hip/hip_runtime.h>
#include <hip/hip_bf16.h>

typedef __bf16 bf16_t;
typedef __bf16 bf16x4 __attribute__((ext_vector_type(4)));
typedef __bf16 bf16x8 __attribute__((ext_vector_type(8)));
typedef float f32x4 __attribute__((ext_vector_type(4)));

#define MFMA16(a, b, c) __builtin_amdgcn_mfma_f32_16x16x32_bf16((a), (b), (c), 0, 0, 0)

#if defined(__has_builtin) && __has_builtin(__builtin_amdgcn_exp2f)
#define EXP2F(x) __builtin_amdgcn_exp2f(x)
#else
#define EXP2F(x) exp2f(x)
#endif

__device__ __forceinline__ void async_copy16(const void* g, void* l) {
#if defined(__has_builtin) && __has_builtin(__builtin_amdgcn_global_load_lds)
  __builtin_amdgcn_global_load_lds((__attribute__((address_space(1))) void*)g,
                                   (__attribute__((address_space(3))) void*)l, 16, 0, 0);
#else
  *(bf16x8*)l = *(const bf16x8*)g;
#endif
}

// tanh-approx GELU in sigmoid form: x*sigmoid(2c(x+0.044715x^3)); |err|<~3e-3
__device__ __forceinline__ float gelu_f(float x) {
  float u = x * (1.5957691216057308f + 0.07135481283f * x * x);
  return x / (1.0f + __expf(-u));
}

// ---------------- weight fp32 -> bf16 converts (merged dispatches) -----------
__global__ __launch_bounds__(256) void cvt4_k(const float* __restrict__ s0,
                                              const float* __restrict__ s1,
                                              const float* __restrict__ s2,
                                              const float* __restrict__ s3,
                                              bf16_t* __restrict__ d0,
                                              bf16_t* __restrict__ d1,
                                              bf16_t* __restrict__ d2,
                                              bf16_t* __restrict__ d3) {
  const int y = blockIdx.y;
  const float* s = (y == 0) ? s0 : (y == 1) ? s1 : (y == 2) ? s2 : s3;
  bf16_t* d = (y == 0) ? d0 : (y == 1) ? d1 : (y == 2) ? d2 : d3;
  int i = (blockIdx.x * 256 + threadIdx.x) * 4;
  float4 f = *(const float4*)(s + i);
  d[i + 0] = (bf16_t)f.x;
  d[i + 1] = (bf16_t)f.y;
  d[i + 2] = (bf16_t)f.z;
  d[i + 3] = (bf16_t)f.w;
}

__global__ __launch_bounds__(256) void cvt2_k(const float* __restrict__ s0,
                                              const float* __restrict__ s1,
                                              bf16_t* __restrict__ d0,
                                              bf16_t* __restrict__ d1) {
  const int y = blockIdx.y;
  const float* s = (y == 0) ? s0 : s1;
  bf16_t* d = (y == 0) ? d0 : d1;
  int i = (blockIdx.x * 256 + threadIdx.x) * 4;
  float4 f = *(const float4*)(s + i);
  d[i + 0] = (bf16_t)f.x;
  d[i + 1] = (bf16_t)f.y;
  d[i + 2] = (bf16_t)f.z;
  d[i + 3] = (bf16_t)f.w;
}

// ---------------- layernorm over 1024 cols, one block per row ----------------
__global__ __launch_bounds__(256) void ln_k(const float* __restrict__ x,
                                            const float* __restrict__ g,
                                            const float* __restrict__ b,
                                            bf16_t* __restrict__ o) {
  __shared__ float red[8];
  const int t = threadIdx.x;
  const size_t row = blockIdx.x;
  float4 xv = ((const float4*)(x + row * 1024))[t];
  float s = xv.x + xv.y + xv.z + xv.w;
  float s2 = xv.x * xv.x + xv.y * xv.y + xv.z * xv.z + xv.w * xv.w;
#pragma unroll
  for (int off = 1; off < 64; off <<= 1) {
    s += __shfl_xor(s, off);
    s2 += __shfl_xor(s2, off);
  }
  if ((t & 63) == 0) {
    red[t >> 6] = s;
    red[4 + (t >> 6)] = s2;
  }
  __syncthreads();
  s = red[0] + red[1] + red[2] + red[3];
  s2 = red[4] + red[5] + red[6] + red[7];
  const float mu = s * (1.0f / 1024.0f);
  const float rstd = rsqrtf(s2 * (1.0f / 1024.0f) - mu * mu + 1e-5f);
  float4 gv = ((const float4*)g)[t];
  float4 bv = ((const float4*)b)[t];
  bf16_t* op = o + row * 1024 + t * 4;
  op[0] = (bf16_t)((xv.x - mu) * rstd * gv.x + bv.x);
  op[1] = (bf16_t)((xv.y - mu) * rstd * gv.y + bv.y);
  op[2] = (bf16_t)((xv.z - mu) * rstd * gv.z + bv.z);
  op[3] = (bf16_t)((xv.w - mu) * rstd * gv.w + bv.w);
}

// ---------------- 128x128xBK32 GEMM, double-buffered K-loop ------------------
// Prefetch next K-tile into alternate LDS buffer right after the barrier;
// one barrier/iter, loads have a full compute phase in flight before drain.
// BK=32 keeps LDS at 32 KB -> 4 blocks/CU.
template <int EPI>
__global__ __launch_bounds__(256, 4) void gemm_bt(const bf16_t* __restrict__ A,
                                                  const bf16_t* __restrict__ W,
                                                  float* __restrict__ Cf,
                                                  bf16_t* __restrict__ Cb,
                                                  const float* __restrict__ bias,
                                                  const float* __restrict__ resid,
                                                  int M, int Nn, int K) {
  __shared__ alignas(16) bf16_t As[2][128 * 32];
  __shared__ alignas(16) bf16_t Bs[2][128 * 32];
  const int t = threadIdx.x;
  const int lane = t & 63;
  const int w = t >> 6;
  const int bm = blockIdx.y * 128;
  const int bn = blockIdx.x * 128;
  const int wm = (w >> 1) * 64;
  const int wn = (w & 1) * 64;
  const int lr = lane & 15;
  const int lq = lane >> 4;
  f32x4 acc[4][4] = {};
  const bf16_t* Ap[2];
  const bf16_t* Bp[2];
#pragma unroll
  for (int c = 0; c < 2; ++c) {
    const int flat = c * 256 + t;  // 0..511 chunks (128 rows x 4 chunks)
    const int r = flat >> 2;
    const int q = flat & 3;
    Ap[c] = A + (size_t)(bm + r) * K + q * 8;
    Bp[c] = W + (size_t)(bn + r) * K + q * 8;
  }
  // prologue: stage k0=0 into buffer 0
#pragma unroll
  for (int c = 0; c < 2; ++c) {
    async_copy16(Ap[c], &As[0][(c * 256 + t) * 8]);
    async_copy16(Bp[c], &Bs[0][(c * 256 + t) * 8]);
  }
  int buf = 0;
  for (int k0 = 0; k0 < K; k0 += 32) {
    __syncthreads();  // drains this buffer's loads (in flight one full iter)
    const int nb = buf ^ 1;
    if (k0 + 32 < K) {
#pragma unroll
      for (int c = 0; c < 2; ++c) {
        async_copy16(Ap[c] + k0 + 32, &As[nb][(c * 256 + t) * 8]);
        async_copy16(Bp[c] + k0 + 32, &Bs[nb][(c * 256 + t) * 8]);
      }
    }
    bf16x8 af[4], bfr[4];
#pragma unroll
    for (int i = 0; i < 4; ++i)
      af[i] = *(const bf16x8*)&As[buf][(wm + i * 16 + lr) * 32 + lq * 8];
#pragma unroll
    for (int j = 0; j < 4; ++j)
      bfr[j] = *(const bf16x8*)&Bs[buf][(wn + j * 16 + lr) * 32 + lq * 8];
#pragma unroll
    for (int i = 0; i < 4; ++i)
#pragma unroll
      for (int j = 0; j < 4; ++j)
        acc[i][j] = MFMA16(af[i], bfr[j], acc[i][j]);
    buf = nb;
  }
#pragma unroll
  for (int i = 0; i < 4; ++i) {
    const int row = bm + wm + i * 16 + lq * 4;
#pragma unroll
    for (int j = 0; j < 4; ++j) {
      const int col = bn + wn + j * 16 + lr;
      float bcol = (EPI >= 1) ? bias[col] : 0.0f;
#pragma unroll
      for (int r = 0; r < 4; ++r) {
        size_t idx = (size_t)(row + r) * Nn + col;
        float vv = acc[i][j][r];
        if (EPI == 0) {
          Cb[idx] = (bf16_t)vv;
        } else if (EPI == 1) {
          Cf[idx] = vv + bcol + resid[idx];
        } else if (EPI == 2) {
          Cb[idx] = (bf16_t)gelu_f(vv + bcol);
        } else {
          Cf[idx] = gelu_f(vv + bcol) + resid[idx];
        }
      }
    }
  }
}

// ---------------- split-K 128x128 GEMM: fp32 partials, dbuf, XCD swizzle -----
__global__ __launch_bounds__(256, 2) void gemm_sk(const bf16_t* __restrict__ A,
                                                  const bf16_t* __restrict__ W,
                                                  float* __restrict__ P0,
                                                  float* __restrict__ P1) {
  const int K = 4096, Nn = 1024;
  __shared__ alignas(16) bf16_t As[2][128 * 64];
  __shared__ alignas(16) bf16_t Bs[2][128 * 64];
  const int t = threadIdx.x;
  const int lane = t & 63;
  const int w = t >> 6;
  const int lin = blockIdx.x + 8 * blockIdx.y;  // 0..255
  const int bm = ((lin & 7) * 4 + ((lin >> 6) & 3)) * 128;
  const int bn = ((lin >> 3) & 7) * 128;
  const int sp = blockIdx.z;
  float* Cf = sp ? P1 : P0;
  const int kbase = sp * 2048;
  const int wm = (w >> 1) * 64;
  const int wn = (w & 1) * 64;
  const int lr = lane & 15;
  const int lq = lane >> 4;
  f32x4 acc[4][4] = {};
  const bf16_t* Ap[4];
  const bf16_t* Bp[4];
#pragma unroll
  for (int c = 0; c < 4; ++c) {
    const int flat = c * 256 + t;
    const int p = flat >> 9;
    const int r = (flat >> 2) & 127;
    const int q = flat & 3;
    Ap[c] = A + (size_t)(bm + r) * K + kbase + p * 32 + q * 8;
    Bp[c] = W + (size_t)(bn + r) * K + kbase + p * 32 + q * 8;
  }
#pragma unroll
  for (int c = 0; c < 4; ++c) {
    async_copy16(Ap[c], &As[0][(c * 256 + t) * 8]);
    async_copy16(Bp[c], &Bs[0][(c * 256 + t) * 8]);
  }
  int buf = 0;
  for (int k0 = 0; k0 < 2048; k0 += 64) {
    __syncthreads();
    const int nb = buf ^ 1;
    if (k0 + 64 < 2048) {
#pragma unroll
      for (int c = 0; c < 4; ++c) {
        async_copy16(Ap[c] + k0 + 64, &As[nb][(c * 256 + t) * 8]);
        async_copy16(Bp[c] + k0 + 64, &Bs[nb][(c * 256 + t) * 8]);
      }
    }
#pragma unroll
    for (int half = 0; half < 2; ++half) {
      const bf16_t* Ash = &As[buf][half * 4096];
      const bf16_t* Bsh = &Bs[buf][half * 4096];
      bf16x8 af[4], bfr[4];
#pragma unroll
      for (int i = 0; i < 4; ++i)
        af[i] = *(const bf16x8*)&Ash[(wm + i * 16 + lr) * 32 + lq * 8];
#pragma unroll
      for (int j = 0; j < 4; ++j)
        bfr[j] = *(const bf16x8*)&Bsh[(wn + j * 16 + lr) * 32 + lq * 8];
#pragma unroll
      for (int i = 0; i < 4; ++i)
#pragma unroll
        for (int j = 0; j < 4; ++j)
          acc[i][j] = MFMA16(af[i], bfr[j], acc[i][j]);
    }
    buf = nb;
  }
#pragma unroll
  for (int i = 0; i < 4; ++i) {
    const int row = bm + wm + i * 16 + lq * 4;
#pragma unroll
    for (int j = 0; j < 4; ++j) {
      const int col = bn + wn + j * 16 + lr;
#pragma unroll
      for (int r = 0; r < 4; ++r)
        Cf[(size_t)(row + r) * Nn + col] = acc[i][j][r];
    }
  }
}

// ---------------- W2 epilogue: dout = gelu(p0+p1+bias) + resid ---------------
__global__ __launch_bounds__(256) void w2_epi(const float* __restrict__ P0,
                                              const float* __restrict__ P1,
                                              const float* __restrict__ bias,
                                              const float* __restrict__ resid,
                                              float* __restrict__ dout) {
  const size_t i = ((size_t)blockIdx.x * 256 + threadIdx.x) * 4;
  const int col = threadIdx.x * 4;
  float4 p0 = *(const float4*)(P0 + i);
  float4 p1 = *(const float4*)(P1 + i);
  float4 bv = *(const float4*)(bias + col);
  float4 rv = *(const float4*)(resid + i);
  float4 o;
  o.x = gelu_f(p0.x + p1.x + bv.x) + rv.x;
  o.y = gelu_f(p0.y + p1.y + bv.y) + rv.y;
  o.z = gelu_f(p0.z + p1.z + bv.z) + rv.z;
  o.w = gelu_f(p0.w + p1.w + bv.w) + rv.w;
  *(float4*)(dout + i) = o;
}

// ---------------- 64x128xBK64 GEMM, dbuf + XCD-locality swizzle --------------
template <int EPI>
__global__ __launch_bounds__(256, 4) void gemm64_bt(const bf16_t* __restrict__ A,
                                                    const bf16_t* __restrict__ W,
                                                    float* __restrict__ Cf,
                                                    const float* __restrict__ bias,
                                                    const float* __restrict__ resid,
                                                    int M, int Nn, int K) {
  __shared__ alignas(16) bf16_t As[2][2 * 64 * 32];
  __shared__ alignas(16) bf16_t Bs[2][2 * 128 * 32];
  const int t = threadIdx.x;
  const int lane = t & 63;
  const int w = t >> 6;
  const int lin = blockIdx.x + 8 * blockIdx.y;
  const int bm = ((lin & 7) * 8 + (lin >> 6)) * 64;
  const int bn = ((lin >> 3) & 7) * 128;
  const int wm = (w >> 1) * 32;
  const int wn = (w & 1) * 64;
  const int lr = lane & 15;
  const int lq = lane >> 4;
  f32x4 acc[2][4] = {};
  const bf16_t* Ap[2];
  const bf16_t* Bp[4];
#pragma unroll
  for (int c = 0; c < 2; ++c) {
    const int flat = c * 256 + t;
    const int p = flat >> 8;
    const int r = (flat >> 2) & 63;
    const int q = flat & 3;
    Ap[c] = A + (size_t)(bm + r) * K + p * 32 + q * 8;
  }
#pragma unroll
  for (int c = 0; c < 4; ++c) {
    const int flat = c * 256 + t;
    const int p = flat >> 9;
    const int r = (flat >> 2) & 127;
    const int q = flat & 3;
    Bp[c] = W + (size_t)(bn + r) * K + p * 32 + q * 8;
  }
#pragma unroll
  for (int c = 0; c < 2; ++c) async_copy16(Ap[c], &As[0][(c * 256 + t) * 8]);
#pragma unroll
  for (int c = 0; c < 4; ++c) async_copy16(Bp[c], &Bs[0][(c * 256 + t) * 8]);
  int buf = 0;
  for (int k0 = 0; k0 < K; k0 += 64) {
    __syncthreads();
    const int nb = buf ^ 1;
    if (k0 + 64 < K) {
#pragma unroll
      for (int c = 0; c < 2; ++c)
        async_copy16(Ap[c] + k0 + 64, &As[nb][(c * 256 + t) * 8]);
#pragma unroll
      for (int c = 0; c < 4; ++c)
        async_copy16(Bp[c] + k0 + 64, &Bs[nb][(c * 256 + t) * 8]);
    }
#pragma unroll
    for (int half = 0; half < 2; ++half) {
      const bf16_t* Ash = &As[buf][half * 2048];
      const bf16_t* Bsh = &Bs[buf][half * 4096];
      bf16x8 af[2], bfr[4];
#pragma unroll
      for (int i = 0; i < 2; ++i)
        af[i] = *(const bf16x8*)&Ash[(wm + i * 16 + lr) * 32 + lq * 8];
#pragma unroll
      for (int j = 0; j < 4; ++j)
        bfr[j] = *(const bf16x8*)&Bsh[(wn + j * 16 + lr) * 32 + lq * 8];
#pragma unroll
      for (int i = 0; i < 2; ++i)
#pragma unroll
        for (int j = 0; j < 4; ++j)
          acc[i][j] = MFMA16(af[i], bfr[j], acc[i][j]);
    }
    buf = nb;
  }
#pragma unroll
  for (int i = 0; i < 2; ++i) {
    const int row = bm + wm + i * 16 + lq * 4;
#pragma unroll
    for (int j = 0; j < 4; ++j) {
      const int col = bn + wn + j * 16 + lr;
      float bcol = bias[col];
#pragma unroll
      for (int r = 0; r < 4; ++r) {
        size_t idx = (size_t)(row + r) * Nn + col;
        float vv = acc[i][j][r];
        if (EPI == 1)
          Cf[idx] = vv + bcol + resid[idx];
        else
          Cf[idx] = gelu_f(vv + bcol) + resid[idx];
      }
    }
  }
}

// ---------------- fused QKV GEMM (BK32 dbuf); Q pre-scaled, V transposed -----
__global__ __launch_bounds__(256, 4) void gemm_qkv(const bf16_t* __restrict__ A,
                                                   const bf16_t* __restrict__ W0,
                                                   const bf16_t* __restrict__ W1,
                                                   const bf16_t* __restrict__ W2,
                                                   bf16_t* __restrict__ C0,
                                                   bf16_t* __restrict__ C1,
                                                   bf16_t* __restrict__ vt) {
  const int z = blockIdx.z;
  const bf16_t* W = (z == 0) ? W0 : ((z == 1) ? W1 : W2);
  const float osc = (z == 0) ? 0.045084220027780106f : 1.0f;
  const int K = 1024, Nn = 1024;
  __shared__ alignas(16) bf16_t As[2][128 * 32];
  __shared__ alignas(16) bf16_t Bs[2][128 * 32];
  const int t = threadIdx.x;
  const int lane = t & 63;
  const int w = t >> 6;
  const int bm = blockIdx.y * 128;
  const int bn = blockIdx.x * 128;
  const int wm = (w >> 1) * 64;
  const int wn = (w & 1) * 64;
  const int lr = lane & 15;
  const int lq = lane >> 4;
  f32x4 acc[4][4] = {};
  const bf16_t* Ap[2];
  const bf16_t* Bp[2];
#pragma unroll
  for (int c = 0; c < 2; ++c) {
    const int flat = c * 256 + t;
    const int r = flat >> 2;
    const int q = flat & 3;
    Ap[c] = A + (size_t)(bm + r) * K + q * 8;
    Bp[c] = W + (size_t)(bn + r) * K + q * 8;
  }
#pragma unroll
  for (int c = 0; c < 2; ++c) {
    async_copy16(Ap[c], &As[0][(c * 256 + t) * 8]);
    async_copy16(Bp[c], &Bs[0][(c * 256 + t) * 8]);
  }
  int buf = 0;
  for (int k0 = 0; k0 < K; k0 += 32) {
    __syncthreads();
    const int nb = buf ^ 1;
    if (k0 + 32 < K) {
#pragma unroll
      for (int c = 0; c < 2; ++c) {
        async_copy16(Ap[c] + k0 + 32, &As[nb][(c * 256 + t) * 8]);
        async_copy16(Bp[c] + k0 + 32, &Bs[nb][(c * 256 + t) * 8]);
      }
    }
    bf16x8 af[4], bfr[4];
#pragma unroll
    for (int i = 0; i < 4; ++i)
      af[i] = *(const bf16x8*)&As[buf][(wm + i * 16 + lr) * 32 + lq * 8];
#pragma unroll
    for (int j = 0; j < 4; ++j)
      bfr[j] = *(const bf16x8*)&Bs[buf][(wn + j * 16 + lr) * 32 + lq * 8];
#pragma unroll
    for (int i = 0; i < 4; ++i)
#pragma unroll
      for (int j = 0; j < 4; ++j)
        acc[i][j] = MFMA16(af[i], bfr[j], acc[i][j]);
    buf = nb;
  }
  if (z == 2) {
    // V transposed: vt[((b*16 + col/64)*64 + col%64)*2048 + n], quad = 4 n's
#pragma unroll
    for (int i = 0; i < 4; ++i) {
      const int row0 = bm + wm + i * 16 + lq * 4;  // n index base
      const int b = row0 >> 11;
      const int n = row0 & 2047;
#pragma unroll
      for (int j = 0; j < 4; ++j) {
        const int col = bn + wn + j * 16 + lr;  // global d (h*64 + dloc)
        bf16x4 pv;
#pragma unroll
        for (int r = 0; r < 4; ++r) pv[r] = (bf16_t)acc[i][j][r];
        *(bf16x4*)&vt[((size_t)(b * 16 + (col >> 6)) * 64 + (col & 63)) * 2048 + n] = pv;
      }
    }
  } else {
    bf16_t* Cb = (z == 0) ? C0 : C1;
#pragma unroll
    for (int i = 0; i < 4; ++i) {
      const int row = bm + wm + i * 16 + lq * 4;
#pragma unroll
      for (int j = 0; j < 4; ++j) {
        const int col = bn + wn + j * 16 + lr;
#pragma unroll
        for (int r = 0; r < 4; ++r)
          Cb[(size_t)(row + r) * Nn + col] = (bf16_t)(acc[i][j][r] * osc);
      }
    }
  }
}

// ---------------- flash attention v9: 128q + split-K + dbuf K/V --------------
__global__ __launch_bounds__(256) void flash_attn(const bf16_t* __restrict__ q,
                                                  const bf16_t* __restrict__ k,
                                                  const bf16_t* __restrict__ vt,
                                                  bf16_t* __restrict__ Opart,
                                                  float* __restrict__ lpart) {
  constexpr int PSP = 72;
  __shared__ alignas(16) bf16_t Ks[2][64 * 64];
  __shared__ alignas(16) bf16_t Vs[2][64 * 64];
  __shared__ alignas(16) bf16_t Ps[4][32 * PSP];
  const int t = threadIdx.x;
  const int lane = t & 63;
  const int w = t >> 6;
  const int lr = lane & 15;
  const int lq = lane >> 4;
  const int qt = blockIdx.x;   // query tile 0..15 (128 wide)
  const int bh = blockIdx.y;   // b*16+h
  const int sp = blockIdx.z;   // key split 0..1
  const int b = bh >> 4;
  const int h = bh & 15;
  const size_t rowbase = (size_t)b * 2048;
  const int hcol = h * 64;
  const bf16_t* vtp = vt + (size_t)bh * 64 * 2048;

  bf16x8 qf[2][2];
#pragma unroll
  for (int u = 0; u < 2; ++u) {
    size_t qrow = rowbase + qt * 128 + w * 32 + u * 16 + lr;
    const bf16_t* qp = q + qrow * 1024 + hcol + lq * 8;
    qf[u][0] = *(const bf16x8*)qp;
    qf[u][1] = *(const bf16x8*)(qp + 32);
  }
  bf16x8 ones;
#pragma unroll
  for (int j = 0; j < 8; ++j) ones[j] = (bf16_t)1.0f;
  f32x4 of[2][4] = {};
  f32x4 ofl[2] = {};

  const int sr0 = t >> 3;
  const int sc0 = (t & 7) ^ (sr0 & 7);
  const int sr1 = (256 + t) >> 3;
  const int sc1 = (t & 7) ^ (sr1 & 7);

  const int kt0 = sp * 16;
  {
    const size_t krow0 = rowbase + (size_t)kt0 * 64;
    async_copy16(k + (krow0 + sr0) * 1024 + hcol + sc0 * 8, &Ks[0][t * 8]);
    async_copy16(vtp + (size_t)sr0 * 2048 + kt0 * 64 + sc0 * 8, &Vs[0][t * 8]);
    async_copy16(k + (krow0 + sr1) * 1024 + hcol + sc1 * 8, &Ks[0][2048 + t * 8]);
    async_copy16(vtp + (size_t)sr1 * 2048 + kt0 * 64 + sc1 * 8, &Vs[0][2048 + t * 8]);
  }
  int buf = 0;
  for (int i = 0; i < 16; ++i) {
    __syncthreads();
    const int nb = buf ^ 1;
    if (i + 1 < 16) {
      const int ktn = kt0 + i + 1;
      const size_t krow0 = rowbase + (size_t)ktn * 64;
      async_copy16(k + (krow0 + sr0) * 1024 + hcol + sc0 * 8, &Ks[nb][t * 8]);
      async_copy16(vtp + (size_t)sr0 * 2048 + ktn * 64 + sc0 * 8, &Vs[nb][t * 8]);
      async_copy16(k + (krow0 + sr1) * 1024 + hcol + sc1 * 8, &Ks[nb][2048 + t * 8]);
      async_copy16(vtp + (size_t)sr1 * 2048 + ktn * 64 + sc1 * 8, &Vs[nb][2048 + t * 8]);
    }
    f32x4 sc[2][4];
#pragma unroll
    for (int s = 0; s < 4; ++s) {
      const int r2 = s * 16 + lr;
      bf16x8 kf0 = *(const bf16x8*)&Ks[buf][r2 * 64 + ((lq) ^ (r2 & 7)) * 8];
      bf16x8 kf1 = *(const bf16x8*)&Ks[buf][r2 * 64 + ((4 + lq) ^ (r2 & 7)) * 8];
#pragma unroll
      for (int u = 0; u < 2; ++u) {
        f32x4 c = {};
        c = MFMA16(kf0, qf[u][0], c);
        c = MFMA16(kf1, qf[u][1], c);
        sc[u][s] = c;
      }
    }
#pragma unroll
    for (int u = 0; u < 2; ++u)
#pragma unroll
      for (int s = 0; s < 4; ++s) {
        bf16x4 pv;
#pragma unroll
        for (int r = 0; r < 4; ++r) pv[r] = (bf16_t)EXP2F(sc[u][s][r]);
        *(bf16x4*)&Ps[w][(u * 16 + lr) * PSP + s * 16 + lq * 4] = pv;
      }
    bf16x8 pf[2][2];
#pragma unroll
    for (int u = 0; u < 2; ++u) {
      pf[u][0] = *(const bf16x8*)&Ps[w][(u * 16 + lr) * PSP + lq * 8];
      pf[u][1] = *(const bf16x8*)&Ps[w][(u * 16 + lr) * PSP + 32 + lq * 8];
      ofl[u] = MFMA16(pf[u][0], ones, ofl[u]);
      ofl[u] = MFMA16(pf[u][1], ones, ofl[u]);
    }
#pragma unroll
    for (int d = 0; d < 4; ++d) {
      const int rv = d * 16 + lr;
      bf16x8 vf0 = *(const bf16x8*)&Vs[buf][rv * 64 + ((lq) ^ (rv & 7)) * 8];
      bf16x8 vf1 = *(const bf16x8*)&Vs[buf][rv * 64 + ((4 + lq) ^ (rv & 7)) * 8];
#pragma unroll
      for (int u = 0; u < 2; ++u) {
        of[u][d] = MFMA16(pf[u][0], vf0, of[u][d]);
        of[u][d] = MFMA16(pf[u][1], vf1, of[u][d]);
      }
    }
    buf = nb;
  }
  bf16_t* Op = Opart + (size_t)sp * 4096 * 1024;
  float* lp = lpart + (size_t)sp * 4096 * 16;
#pragma unroll
  for (int u = 0; u < 2; ++u) {
    const size_t grow0 = rowbase + qt * 128 + w * 32 + u * 16 + lq * 4;
#pragma unroll
    for (int r = 0; r < 4; ++r) {
#pragma unroll
      for (int d = 0; d < 4; ++d)
        Op[(grow0 + r) * 1024 + hcol + d * 16 + lr] = (bf16_t)of[u][d][r];
      if (lr == 0) lp[(grow0 + r) * 16 + h] = ofl[u][r];
    }
  }
}

// ---------------- split-K combine: attn = (O0+O1)/(l0+l1) --------------------
__global__ __launch_bounds__(256) void combine_k(const bf16_t* __restrict__ Opart,
                                                 const float* __restrict__ lpart,
                                                 bf16_t* __restrict__ attn) {
  const size_t row = blockIdx.x;
  const int t = threadIdx.x;
  const int h = t >> 4;
  const float inv =
      1.0f / (lpart[row * 16 + h] + lpart[4096 * 16 + row * 16 + h]);
  const size_t i = row * 1024 + t * 4;
  bf16x4 a = *(const bf16x4*)&Opart[i];
  bf16x4 bvv = *(const bf16x4*)&Opart[(size_t)4096 * 1024 + i];
  bf16x4 o;
#pragma unroll
  for (int j = 0; j < 4; ++j) o[j] = (bf16_t)(((float)a[j] + (float)bvv[j]) * inv);
  *(bf16x4*)&attn[i] = o;
}

extern "C" void kernel_launch(void* const* d_in, const int* in_sizes, int n_in,
                              void* d_out, int out_size, void* d_ws, size_t ws_size,
                              hipStream_t stream) {
  (void)in_sizes;
  (void)n_in;
  (void)out_size;
  (void)ws_size;
  const float* x = (const float*)d_in[0];
  const float* la1g = (const float*)d_in[1];
  const float* la1b = (const float*)d_in[2];
  const float* Wq = (const float*)d_in[3];
  const float* Wk = (const float*)d_in[4];
  const float* Wv = (const float*)d_in[5];
  const float* Wo = (const float*)d_in[6];
  const float* bo = (const float*)d_in[7];
  const float* la2g = (const float*)d_in[8];
  const float* la2b = (const float*)d_in[9];
  const float* W1 = (const float*)d_in[10];
  const float* b1 = (const float*)d_in[11];
  const float* W2 = (const float*)d_in[12];
  const float* b2 = (const float*)d_in[13];
  char* ws = (char*)d_ws;
  const size_t MB = (size_t)1 << 20;
  bf16_t* wq_b = (bf16_t*)(ws + 0 * MB);
  bf16_t* wk_b = (bf16_t*)(ws + 2 * MB);
  bf16_t* wv_b = (bf16_t*)(ws + 4 * MB);
  bf16_t* wo_b = (bf16_t*)(ws + 6 * MB);
  bf16_t* w1_b = (bf16_t*)(ws + 8 * MB);
  bf16_t* w2_b = (bf16_t*)(ws + 16 * MB);
  bf16_t* hbuf = (bf16_t*)(ws + 24 * MB);  // ln1 out, QKV input
  bf16_t* qb = (bf16_t*)(ws + 32 * MB);
  bf16_t* kb = (bf16_t*)(ws + 40 * MB);
  bf16_t* vt = (bf16_t*)(ws + 48 * MB);    // V written transposed by QKV
  bf16_t* attn = (bf16_t*)(ws + 56 * MB);
  float* outb = (float*)(ws + 64 * MB);    // 16 MB fp32
  bf16_t* h2 = (bf16_t*)(ws + 80 * MB);    // 8 MB
  bf16_t* m1 = (bf16_t*)(ws + 88 * MB);    // 32 MB (88-120)
  // flash split-K scratch (dead after combine): overlays outb/h2 slots
  bf16_t* Opart = (bf16_t*)(ws + 64 * MB); // 2 x 8 MB bf16
  float* lpart = (float*)(ws + 80 * MB);   // 512 KB fp32
  // W2 split-K partials: overlay slots dead after flash (hbuf/qb, kb/vt)
  float* p0 = (float*)(ws + 24 * MB);      // 16 MB fp32 (24-40)
  float* p1 = (float*)(ws + 40 * MB);      // 16 MB fp32 (40-56)
  float* dout = (float*)d_out;

  cvt4_k<<<dim3(1024, 4), 256, 0, stream>>>(Wq, Wk, Wv, Wo, wq_b, wk_b, wv_b, wo_b);
  cvt2_k<<<dim3(4096, 2), 256, 0, stream>>>(W1, W2, w1_b, w2_b);
  ln_k<<<4096, 256, 0, stream>>>(x, la1g, la1b, hbuf);
  gemm_qkv<<<dim3(8, 32, 3), 256, 0, stream>>>(hbuf, wq_b, wk_b, wv_b, qb, kb, vt);
  flash_attn<<<dim3(16, 32, 2), 256, 0, stream>>>(qb, kb, vt, Opart, lpart);
  combine_k<<<4096, 256, 0, stream>>>(Opart, lpart, attn);
  gemm64_bt<1><<<dim3(8, 64), 256, 0, stream>>>(attn, wo_b, outb, bo, x, 4096, 1024, 1024);
  ln_k<<<4096, 256, 0, stream>>>(outb, la2g, la2b, h2);
  gemm_bt<2><<<dim3(32, 32), 256, 0, stream>>>(h2, w1_b, nullptr, m1, b1, nullptr, 4096, 4096, 1024);
  gemm_sk<<<dim3(8, 32, 2), 256, 0, stream>>>(m1, w2_b, p0, p1);
  w2_epi<<<4096, 256, 0, stream>>>(p0, p1, b2, outb, dout);
}